// Round 3
// baseline (909.734 us; speedup 1.0000x reference)
//
#include <hip/hip_runtime.h>
#include <hip/hip_bf16.h>
#include <stdint.h>

// MambaConditioningBlock on gfx950.
// B=4, L=2048, D_MODEL=1024, D_INNER=2048, D_STATE=16, DT_RANK=64, D_CONV=4.
// R3 change: R2's chunked scan overflowed d_ws (+12.6MB past the known-good
// footprint) -> OOB stores corrupted the harness's pristine input copies ->
// post-timing divergence. Fix: alias hloc/Pp/hin into the h_bf/part_T region
// (16MB, dead after k_xsplit, before scanA). ws footprint back to R1's 233.6MB.

#define L_ 2048
#define DM 1024
#define DI 2048
#define DS 16
#define NC 8     // scan chunks
#define TC 256   // steps per chunk

typedef __bf16 bf16x8 __attribute__((ext_vector_type(8)));
typedef float f32x4 __attribute__((ext_vector_type(4)));

__device__ __forceinline__ float bf2f(unsigned int u) {
  union { unsigned int i; float f; } c;
  c.i = (u & 0xFFFFu) << 16;
  return c.f;
}
__device__ __forceinline__ unsigned short f2bf(float f) {
  union { float f; unsigned int i; } c; c.f = f;
  unsigned int x = c.i;
  return (unsigned short)((x + 0x7FFFu + ((x >> 16) & 1u)) >> 16);  // RNE
}
__device__ __forceinline__ float silu_f(float v) { return v / (1.f + __expf(-v)); }

// ---- DPP row-16 sum (VALU pipe) ----
template<int CTRL>
__device__ __forceinline__ float dpp_add(float v) {
  union { float f; int i; } c; c.f = v;
  int p = __builtin_amdgcn_update_dpp(0, c.i, CTRL, 0xF, 0xF, true);
  union { int i; float f; } r; r.i = p;
  return v + r.f;
}
__device__ __forceinline__ float row16_sum(float v) {
  v = dpp_add<0xB1>(v);   // quad_perm [1,0,3,2]
  v = dpp_add<0x4E>(v);   // quad_perm [2,3,0,1]
  v = dpp_add<0x141>(v);  // row_half_mirror
  v = dpp_add<0x140>(v);  // row_mirror
  return v;               // all 16 lanes of the row hold the sum
}

// ---- async global->LDS, 16B per lane ----
__device__ __forceinline__ void async_cp16(unsigned short* lds, const unsigned short* g) {
  __builtin_amdgcn_global_load_lds(
      (const __attribute__((address_space(1))) unsigned int*)g,
      (__attribute__((address_space(3))) unsigned int*)lds, 16, 0, 0);
}

// =================== weight transpose+convert: src[K][N] fp32 -> dst[NP][K] bf16 ===================
__global__ __launch_bounds__(256) void k_wt(const float* __restrict__ src,
                                            unsigned short* __restrict__ dst,
                                            int K, int N, int NP) {
  __shared__ float tile[32][33];
  const int kb = blockIdx.x * 32, nb = blockIdx.y * 32;
  const int tx = threadIdx.x & 31, ty = threadIdx.x >> 5;
#pragma unroll
  for (int i = 0; i < 4; i++) {
    int k = kb + ty + 8 * i, n = nb + tx;
    float v = 0.f;
    if (k < K && n < N) v = src[(size_t)k * N + n];
    tile[ty + 8 * i][tx] = v;
  }
  __syncthreads();
#pragma unroll
  for (int i = 0; i < 4; i++) {
    int n = nb + ty + 8 * i, k = kb + tx;
    if (n < NP && k < K) dst[(size_t)n * K + k] = f2bf(tile[tx][ty + 8 * i]);
  }
}

// =================== mod = silu(c) @ W_ada + b_ada ===================
__global__ __launch_bounds__(256) void k_ada(const float* __restrict__ c,
                                             const float* __restrict__ W,
                                             const float* __restrict__ bias,
                                             float* __restrict__ mod) {
  __shared__ float sc[DM];
  const int b = blockIdx.y, tid = threadIdx.x;
  for (int k = tid; k < DM; k += 256) sc[k] = silu_f(c[b * DM + k]);
  __syncthreads();
  const int j = blockIdx.x * 256 + tid;
  float acc = bias[j];
#pragma unroll 8
  for (int k = 0; k < DM; k++) acc += sc[k] * W[(size_t)k * 3072 + j];
  mod[b * 3072 + j] = acc;
}

// =================== LayerNorm + adaLN modulation -> bf16 ===================
__global__ __launch_bounds__(256) void k_ln(const float* __restrict__ x,
                                            const float* __restrict__ mod,
                                            unsigned short* __restrict__ h) {
  const int row = blockIdx.x, b = row >> 11, tid = threadIdx.x;
  const float4 v = ((const float4*)(x + (size_t)row * DM))[tid];
  float s = v.x + v.y + v.z + v.w;
  float ss = v.x * v.x + v.y * v.y + v.z * v.z + v.w * v.w;
#pragma unroll
  for (int off = 32; off; off >>= 1) { s += __shfl_down(s, off); ss += __shfl_down(ss, off); }
  __shared__ float red[10];
  const int wv = tid >> 6, ln = tid & 63;
  if (ln == 0) { red[wv] = s; red[4 + wv] = ss; }
  __syncthreads();
  if (tid == 0) {
    float st = red[0] + red[1] + red[2] + red[3];
    float sst = red[4] + red[5] + red[6] + red[7];
    float mu = st * (1.f / DM);
    red[8] = mu;
    red[9] = rsqrtf(sst * (1.f / DM) - mu * mu + 1e-6f);
  }
  __syncthreads();
  const float mu = red[8], rstd = red[9];
  const int ccol = tid * 4;
  const float4 sc = *(const float4*)(mod + b * 3072 + ccol);
  const float4 sh = *(const float4*)(mod + b * 3072 + DM + ccol);
  uint2 p;
  p.x = (unsigned)f2bf((v.x - mu) * rstd * (1.f + sc.x) + sh.x) |
        ((unsigned)f2bf((v.y - mu) * rstd * (1.f + sc.y) + sh.y) << 16);
  p.y = (unsigned)f2bf((v.z - mu) * rstd * (1.f + sc.z) + sh.z) |
        ((unsigned)f2bf((v.w - mu) * rstd * (1.f + sc.w) + sh.w) << 16);
  *(uint2*)(h + (size_t)row * DM + ccol) = p;
}

// =================== bf16 MFMA GEMM, 128x128 tile, m97 structure ===================
struct GArgs {
  const unsigned short* A;
  const unsigned short* Bt;
  int lda, ldb, klen;
  float* f0;
  unsigned short* h0;
  unsigned short* h1;
  const float* c0;
  const float* c1;
};

template<int EPI>
__global__ __launch_bounds__(256, 2) void k_gemm(GArgs g) {
  __shared__ unsigned short sA[128 * 32];
  __shared__ unsigned short sB[128 * 32];
  const int tid = threadIdx.x;
  const int w = tid >> 6, lane = tid & 63;
  const int m0 = blockIdx.x * 128, n0 = blockIdx.y * 128;
  const int kstart = blockIdx.z * g.klen;
  const int r4 = lane >> 2;
  const int c8 = (lane & 3) * 8;
  const int rowA0 = w * 16 + r4, rowA1 = (w + 4) * 16 + r4;
  const unsigned short* gA0 = g.A + (size_t)(m0 + rowA0) * g.lda + kstart + c8;
  const unsigned short* gA1 = g.A + (size_t)(m0 + rowA1) * g.lda + kstart + c8;
  const unsigned short* gB0 = g.Bt + (size_t)(n0 + rowA0) * g.ldb + kstart + c8;
  const unsigned short* gB1 = g.Bt + (size_t)(n0 + rowA1) * g.ldb + kstart + c8;
  unsigned short* lA0 = sA + w * 512;
  unsigned short* lA1 = sA + (w + 4) * 512;
  unsigned short* lB0 = sB + w * 512;
  unsigned short* lB1 = sB + (w + 4) * 512;
  const int mw = (w & 1) * 64, nw = (w >> 1) * 64;
  const int row16 = lane & 15, k8 = (lane >> 4) * 8;
  f32x4 acc[4][4] = {};
  for (int kk = 0; kk < g.klen; kk += 32) {
    async_cp16(lA0, gA0); async_cp16(lA1, gA1);
    async_cp16(lB0, gB0); async_cp16(lB1, gB1);
    gA0 += 32; gA1 += 32; gB0 += 32; gB1 += 32;
    __syncthreads();
    bf16x8 av[4], bv[4];
#pragma unroll
    for (int i = 0; i < 4; i++)
      av[i] = *(const bf16x8*)(sA + (mw + 16 * i + row16) * 32 + k8);
#pragma unroll
    for (int j = 0; j < 4; j++)
      bv[j] = *(const bf16x8*)(sB + (nw + 16 * j + row16) * 32 + k8);
#pragma unroll
    for (int i = 0; i < 4; i++)
#pragma unroll
      for (int j = 0; j < 4; j++)
        acc[i][j] = __builtin_amdgcn_mfma_f32_16x16x32_bf16(av[i], bv[j], acc[i][j], 0, 0, 0);
    __syncthreads();
  }
  const int qr = (lane >> 4) * 4, cn = lane & 15;
#pragma unroll
  for (int i = 0; i < 4; i++) {
    const int m = m0 + mw + 16 * i + qr;
    const int b = m >> 11, t = m & 2047;
#pragma unroll
    for (int j = 0; j < 4; j++) {
      const int n = n0 + nw + 16 * j + cn;
      f32x4 v = acc[i][j];
      if constexpr (EPI == 0) {
        uint2 p;
        p.x = (unsigned)f2bf(v[0]) | ((unsigned)f2bf(v[1]) << 16);
        p.y = (unsigned)f2bf(v[2]) | ((unsigned)f2bf(v[3]) << 16);
        unsigned short* dst = (n < DI)
            ? g.h0 + ((size_t)b << 22) + (size_t)n * L_ + t
            : g.h1 + ((size_t)b << 22) + (size_t)(n - DI) * L_ + t;
        *(uint2*)dst = p;
      } else if constexpr (EPI == 1) {
        *(f32x4*)(g.f0 + ((size_t)(blockIdx.z * 128 + n)) * 8192 + m) = v;
      } else if constexpr (EPI == 2) {
        const float bn = g.c0[n];
        f32x4 o;
#pragma unroll
        for (int r = 0; r < 4; r++) {
          float xx = v[r] + bn;
          o[r] = (xx > 15.f) ? xx : __logf(1.f + __expf(xx));
        }
        *(f32x4*)(g.f0 + ((size_t)b << 22) + (size_t)n * L_ + t) = o;
      } else {
        const float gate = g.c1[b * 3072 + 2048 + n];
#pragma unroll
        for (int r = 0; r < 4; r++) {
          size_t idx = (size_t)(m + r) * DM + n;
          g.f0[idx] = g.c0[idx] + gate * v[r];
        }
      }
    }
  }
}

// =================== causal depthwise conv (k=4) + silu ===================
__global__ __launch_bounds__(256) void k_conv(const unsigned short* __restrict__ xmT,
                                              const float* __restrict__ conv_w,
                                              const float* __restrict__ conv_b,
                                              unsigned short* __restrict__ uT,
                                              unsigned short* __restrict__ xc) {
  __shared__ unsigned short sT[32][33];
  const int b = blockIdx.z, t0 = blockIdx.x * 32, d0 = blockIdx.y * 32;
  const int tid = threadIdx.x;
  const int tq = tid & 7, dx = tid >> 3;
  const int d = d0 + dx;
  const int tg = t0 + tq * 4;
  const unsigned short* src = xmT + ((size_t)b << 22) + (size_t)d * L_;
  uint2 wA = make_uint2(0u, 0u);
  if (tg >= 4) wA = *(const uint2*)(src + tg - 4);
  const uint2 wB = *(const uint2*)(src + tg);
  float xw[8];
  xw[0] = bf2f(wA.x); xw[1] = bf2f(wA.x >> 16);
  xw[2] = bf2f(wA.y); xw[3] = bf2f(wA.y >> 16);
  xw[4] = bf2f(wB.x); xw[5] = bf2f(wB.x >> 16);
  xw[6] = bf2f(wB.y); xw[7] = bf2f(wB.y >> 16);
  const float w0 = conv_w[d * 4 + 0], w1 = conv_w[d * 4 + 1];
  const float w2 = conv_w[d * 4 + 2], w3 = conv_w[d * 4 + 3];
  const float cb = conv_b[d];
  unsigned short rb[4];
#pragma unroll
  for (int i = 0; i < 4; i++) {
    float a = cb + w0 * xw[i + 1] + w1 * xw[i + 2] + w2 * xw[i + 3] + w3 * xw[i + 4];
    rb[i] = f2bf(silu_f(a));
  }
  uint2 p;
  p.x = (unsigned)rb[0] | ((unsigned)rb[1] << 16);
  p.y = (unsigned)rb[2] | ((unsigned)rb[3] << 16);
  *(uint2*)(uT + ((size_t)b << 22) + (size_t)d * L_ + tg) = p;
  const int tl0 = tq * 4;
#pragma unroll
  for (int i = 0; i < 4; i++) sT[tl0 + i][dx] = rb[i];
  __syncthreads();
  const int dl2 = tid & 31, tb2 = tid >> 5;
#pragma unroll
  for (int i = 0; i < 4; i++) {
    int tl = tb2 + 8 * i;
    xc[((size_t)b * L_ + t0 + tl) * (size_t)DI + d0 + dl2] = sT[tl][dl2];
  }
}

// =================== reduce split-K partials, split dt/B/C ===================
__global__ __launch_bounds__(256) void k_xsplit(const float* __restrict__ pt,
                                                unsigned short* __restrict__ dtb,
                                                float* __restrict__ BTo,
                                                float* __restrict__ CTo) {
  const int bx = blockIdx.x;
  const int n = bx >> 5;
  const int m = ((bx & 31) << 8) + threadIdx.x;
  float v = pt[(size_t)n * 8192 + m] + pt[(size_t)(128 + n) * 8192 + m] +
            pt[(size_t)(256 + n) * 8192 + m] + pt[(size_t)(384 + n) * 8192 + m];
  const int b = m >> 11, t = m & 2047;
  if (n < 64) dtb[(size_t)m * 64 + n] = f2bf(v);
  else if (n < 80) BTo[b * (DS * L_) + (n - 64) * L_ + t] = v;
  else CTo[b * (DS * L_) + (n - 80) * L_ + t] = v;
}

// =================== chunked scan, phase A: local scan (h0=0), emit P and h_loc ===================
// grid (128, 4, NC-1); thread per (d_local, s)
__global__ __launch_bounds__(256, 8) void k_scanA(const float* __restrict__ dT,
                                                  const unsigned short* __restrict__ uT,
                                                  const float* __restrict__ BT,
                                                  const float* __restrict__ A_log,
                                                  float* __restrict__ hloc,
                                                  float* __restrict__ Pout) {
  const int b = blockIdx.y, c = blockIdx.z;
  const int d0 = blockIdx.x * 16;
  const int tid = threadIdx.x, dl = tid >> 4, s = tid & 15;
  const int d = d0 + dl;
  const float* dp = dT + ((size_t)b << 22) + (size_t)d * L_ + c * TC;
  const unsigned short* up = uT + ((size_t)b << 22) + (size_t)d * L_ + c * TC;
  const float* bp = BT + b * (DS * L_) + s * L_ + c * TC;
  const float Av = -__expf(A_log[d * DS + s]);
  float h = 0.f, P = 1.f;
  for (int t0 = 0; t0 < TC; t0 += 8) {
    const f32x4 dva = *(const f32x4*)(dp + t0);
    const f32x4 dvb = *(const f32x4*)(dp + t0 + 4);
    const f32x4 ba = *(const f32x4*)(bp + t0);
    const f32x4 bb = *(const f32x4*)(bp + t0 + 4);
    const uint4 ur = *(const uint4*)(up + t0);
    const float uv[8] = {bf2f(ur.x), bf2f(ur.x >> 16), bf2f(ur.y), bf2f(ur.y >> 16),
                         bf2f(ur.z), bf2f(ur.z >> 16), bf2f(ur.w), bf2f(ur.w >> 16)};
#pragma unroll
    for (int i = 0; i < 8; i++) {
      const float dv = (i < 4) ? dva[i] : dvb[i - 4];
      const float bv = (i < 4) ? ba[i] : bb[i - 4];
      const float a = __expf(dv * Av);
      P *= a;
      h = a * h + (dv * uv[i]) * bv;
    }
  }
  const size_t idx = (((size_t)b * NC + c) * 2048 + d) * 16 + s;
  hloc[idx] = h;
  Pout[idx] = P;
}

// =================== phase B: prefix over chunks ===================
__global__ __launch_bounds__(256) void k_scanB(const float* __restrict__ hloc,
                                               const float* __restrict__ P,
                                               float* __restrict__ hin) {
  const int i = blockIdx.x * 256 + threadIdx.x;   // 131072
  const int b = i >> 15, rem = i & 32767;         // rem = d*16+s
  const size_t base = (size_t)b * NC * 32768 + rem;
  float H = 0.f;
#pragma unroll
  for (int c = 0; c < NC; c++) {
    const size_t idx = base + (size_t)c * 32768;
    hin[idx] = H;
    if (c < NC - 1) H = P[idx] * H + hloc[idx];
  }
}

// =================== phase C: apply carry, compute y (fused skip + silu(z) gate) ===================
// grid (128, 4, NC)
__global__ __launch_bounds__(256, 8) void k_scanC(const float* __restrict__ dT,
                                                  const unsigned short* __restrict__ uT,
                                                  const unsigned short* __restrict__ zT,
                                                  const float* __restrict__ BT,
                                                  const float* __restrict__ CT,
                                                  const float* __restrict__ A_log,
                                                  const float* __restrict__ Dsk,
                                                  const float* __restrict__ hin,
                                                  unsigned short* __restrict__ y) {
  const int b = blockIdx.y, c = blockIdx.z;
  const int d0 = blockIdx.x * 16;
  const int tid = threadIdx.x, dl = tid >> 4, s = tid & 15;
  const int d = d0 + dl;
  const float* dp = dT + ((size_t)b << 22) + (size_t)d * L_ + c * TC;
  const unsigned short* up = uT + ((size_t)b << 22) + (size_t)d * L_ + c * TC;
  const unsigned short* zp = zT + ((size_t)b << 22) + (size_t)d * L_ + c * TC;
  const float* bp = BT + b * (DS * L_) + s * L_ + c * TC;
  const float* cp = CT + b * (DS * L_) + s * L_ + c * TC;
  const float Av = -__expf(A_log[d * DS + s]);
  const float dsk = Dsk[d];
  unsigned short* yp = y + ((size_t)(b * L_ + c * TC)) * DI + d;
  float h = hin[(((size_t)b * NC + c) * 2048 + d) * 16 + s];
  for (int t0 = 0; t0 < TC; t0 += 8) {
    const f32x4 dva = *(const f32x4*)(dp + t0);
    const f32x4 dvb = *(const f32x4*)(dp + t0 + 4);
    const f32x4 ba = *(const f32x4*)(bp + t0);
    const f32x4 bb = *(const f32x4*)(bp + t0 + 4);
    const f32x4 ca = *(const f32x4*)(cp + t0);
    const f32x4 cb4 = *(const f32x4*)(cp + t0 + 4);
    const uint4 ur = *(const uint4*)(up + t0);
    const uint4 zr = *(const uint4*)(zp + t0);
    const float uv0 = bf2f(ur.x), uv1 = bf2f(ur.x >> 16);
    const float uv2 = bf2f(ur.y), uv3 = bf2f(ur.y >> 16);
    const float uv4 = bf2f(ur.z), uv5 = bf2f(ur.z >> 16);
    const float uv6 = bf2f(ur.w), uv7 = bf2f(ur.w >> 16);
    float a, y0, y1, y2, y3;
    a = __expf(dva[0] * Av); h = a * h + (dva[0] * uv0) * ba[0]; y0 = row16_sum(h * ca[0]);
    a = __expf(dva[1] * Av); h = a * h + (dva[1] * uv1) * ba[1]; y1 = row16_sum(h * ca[1]);
    a = __expf(dva[2] * Av); h = a * h + (dva[2] * uv2) * ba[2]; y2 = row16_sum(h * ca[2]);
    a = __expf(dva[3] * Av); h = a * h + (dva[3] * uv3) * ba[3]; y3 = row16_sum(h * ca[3]);
    if (s < 4) {
      const unsigned zsel = (s < 2) ? zr.x : zr.y;
      const float zv = bf2f((s & 1) ? (zsel >> 16) : zsel);
      const float uv = (s == 0) ? uv0 : (s == 1) ? uv1 : (s == 2) ? uv2 : uv3;
      const float yv = (s == 0) ? y0 : (s == 1) ? y1 : (s == 2) ? y2 : y3;
      yp[(size_t)(t0 + s) * DI] = f2bf((yv + uv * dsk) * silu_f(zv));
    }
    a = __expf(dvb[0] * Av); h = a * h + (dvb[0] * uv4) * bb[0]; y0 = row16_sum(h * cb4[0]);
    a = __expf(dvb[1] * Av); h = a * h + (dvb[1] * uv5) * bb[1]; y1 = row16_sum(h * cb4[1]);
    a = __expf(dvb[2] * Av); h = a * h + (dvb[2] * uv6) * bb[2]; y2 = row16_sum(h * cb4[2]);
    a = __expf(dvb[3] * Av); h = a * h + (dvb[3] * uv7) * bb[3]; y3 = row16_sum(h * cb4[3]);
    if (s < 4) {
      const unsigned zsel = (s < 2) ? zr.z : zr.w;
      const float zv = bf2f((s & 1) ? (zsel >> 16) : zsel);
      const float uv = (s == 0) ? uv4 : (s == 1) ? uv5 : (s == 2) ? uv6 : uv7;
      const float yv = (s == 0) ? y0 : (s == 1) ? y1 : (s == 2) ? y2 : y3;
      yp[(size_t)(t0 + 4 + s) * DI] = f2bf((yv + uv * dsk) * silu_f(zv));
    }
  }
}

// =================== launch ===================
extern "C" void kernel_launch(void* const* d_in, const int* in_sizes, int n_in,
                              void* d_out, int out_size, void* d_ws, size_t ws_size,
                              hipStream_t stream) {
  const float* x      = (const float*)d_in[0];
  const float* c      = (const float*)d_in[1];
  const float* W_in   = (const float*)d_in[2];
  const float* conv_w = (const float*)d_in[3];
  const float* conv_b = (const float*)d_in[4];
  const float* W_xp   = (const float*)d_in[5];
  const float* W_dt   = (const float*)d_in[6];
  const float* b_dt   = (const float*)d_in[7];
  const float* A_log  = (const float*)d_in[8];
  const float* D_skip = (const float*)d_in[9];
  const float* W_out  = (const float*)d_in[10];
  const float* W_ada  = (const float*)d_in[11];
  const float* b_ada  = (const float*)d_in[12];
  float* out = (float*)d_out;

  char* ws = (char*)d_ws;
  size_t off = 0;
  auto take = [&](size_t bytes) {
    char* p = ws + off;
    off += (bytes + 255) & ~(size_t)255;
    return p;
  };
  // Footprint identical to R1 (known to fit ws_size). Scan temporaries are
  // carved out of the h_bf/part_T region below, NOT appended.
  float* mod             = (float*)take((size_t)4 * 3072 * 4);
  unsigned short* Wt_in  = (unsigned short*)take((size_t)4096 * 1024 * 2);
  unsigned short* Wt_out = (unsigned short*)take((size_t)1024 * 2048 * 2);
  unsigned short* Wt_xp  = (unsigned short*)take((size_t)128 * 2048 * 2);
  unsigned short* Wt_dt  = (unsigned short*)take((size_t)2048 * 64 * 2);
  unsigned short* h_bf   = (unsigned short*)take((size_t)8192 * 1024 * 2);      // 16MB; reused: part_T, then hloc/Pp/hin
  unsigned short* xm_T   = (unsigned short*)take((size_t)4 * 2048 * 2048 * 2);  // reused as y_bf
  unsigned short* z_T    = (unsigned short*)take((size_t)4 * 2048 * 2048 * 2);
  unsigned short* u_T    = (unsigned short*)take((size_t)4 * 2048 * 2048 * 2);
  unsigned short* xc     = (unsigned short*)take((size_t)8192 * 2048 * 2);
  float* delta_T         = (float*)take((size_t)4 * 2048 * 2048 * 4);
  unsigned short* dt_bf  = (unsigned short*)take((size_t)8192 * 64 * 2);
  float* B_T             = (float*)take((size_t)4 * 16 * 2048 * 4);
  float* C_T             = (float*)take((size_t)4 * 16 * 2048 * 4);
  float* part_T = (float*)h_bf;   // 16MB region; dead after k_xsplit
  // scan temporaries (4MB each, 12MB total) alias part_T's region after k_xsplit:
  float* hloc = (float*)h_bf;
  float* Pp   = (float*)(h_bf + (size_t)2 * 1024 * 1024);   // +4MB (ushort units)
  float* hin  = (float*)(h_bf + (size_t)4 * 1024 * 1024);   // +8MB
  unsigned short* y_bf = xm_T;    // xm_T dead after conv

  // 1. weight convert+transpose
  k_wt<<<dim3(32, 128), 256, 0, stream>>>(W_in, Wt_in, 1024, 4096, 4096);
  k_wt<<<dim3(64, 32), 256, 0, stream>>>(W_out, Wt_out, 2048, 1024, 1024);
  k_wt<<<dim3(64, 4), 256, 0, stream>>>(W_xp, Wt_xp, 2048, 96, 128);
  k_wt<<<dim3(2, 64), 256, 0, stream>>>(W_dt, Wt_dt, 64, 2048, 2048);
  // 2. conditioning
  k_ada<<<dim3(12, 4), 256, 0, stream>>>(c, W_ada, b_ada, mod);
  // 3. LN + modulation
  k_ln<<<8192, 256, 0, stream>>>(x, mod, h_bf);
  // 4. in-proj
  GArgs a1{h_bf, Wt_in, 1024, 1024, 1024, nullptr, xm_T, z_T, nullptr, nullptr};
  k_gemm<0><<<dim3(64, 32), 256, 0, stream>>>(a1);
  // 5. conv + silu
  k_conv<<<dim3(64, 64, 4), 256, 0, stream>>>(xm_T, conv_w, conv_b, u_T, xc);
  // 6. x-proj (split-K)
  GArgs a2{xc, Wt_xp, 2048, 2048, 512, part_T, nullptr, nullptr, nullptr, nullptr};
  k_gemm<1><<<dim3(64, 1, 4), 256, 0, stream>>>(a2);
  // 7. reduce + split
  k_xsplit<<<3072, 256, 0, stream>>>(part_T, dt_bf, B_T, C_T);
  // 8. dt-proj + softplus
  GArgs a3{dt_bf, Wt_dt, 64, 64, 64, delta_T, nullptr, nullptr, b_dt, nullptr};
  k_gemm<2><<<dim3(64, 16), 256, 0, stream>>>(a3);
  // 9. chunked selective scan (temporaries live in dead part_T region)
  k_scanA<<<dim3(128, 4, NC - 1), 256, 0, stream>>>(delta_T, u_T, B_T, A_log, hloc, Pp);
  k_scanB<<<512, 256, 0, stream>>>(hloc, Pp, hin);
  k_scanC<<<dim3(128, 4, NC), 256, 0, stream>>>(delta_T, u_T, z_T, B_T, C_T, A_log, D_skip, hin, y_bf);
  // 10. out-proj + residual + gate
  GArgs a4{y_bf, Wt_out, 2048, 2048, 2048, out, nullptr, nullptr, x, mod};
  k_gemm<3><<<dim3(64, 8), 256, 0, stream>>>(a4);
}

// Round 4
// 715.752 us; speedup vs baseline: 1.2710x; 1.2710x over previous
//
#include <hip/hip_runtime.h>
#include <hip/hip_bf16.h>
#include <stdint.h>

// MambaConditioningBlock on gfx950.
// B=4, L=2048, D_MODEL=1024, D_INNER=2048, D_STATE=16, DT_RANK=64, D_CONV=4.
// R4 change: scan restructured to thread-per-(b,d) with all 16 states in
// registers. Removes the 16x redundant per-s work and the per-step DPP
// reduction (was ~240 VALU lane-ops per (d,step), now ~55). B/C repacked to
// [b][t][32] (wave-uniform per-step loads). Chunked (NC=32, TC=64):
// A=local scan + sum(delta), B=per-(b,d) chunk prefix, C=carry + y epilogue.
// Scan temporaries alias dead regions (xc: hloc+dsum; h_bf: hin) - no ws growth.

#define L_ 2048
#define DM 1024
#define DI 2048
#define DS 16
#define NC 32    // scan chunks
#define TC 64    // steps per chunk

typedef __bf16 bf16x8 __attribute__((ext_vector_type(8)));
typedef float f32x4 __attribute__((ext_vector_type(4)));

__device__ __forceinline__ float bf2f(unsigned int u) {
  union { unsigned int i; float f; } c;
  c.i = (u & 0xFFFFu) << 16;
  return c.f;
}
__device__ __forceinline__ unsigned short f2bf(float f) {
  union { float f; unsigned int i; } c; c.f = f;
  unsigned int x = c.i;
  return (unsigned short)((x + 0x7FFFu + ((x >> 16) & 1u)) >> 16);  // RNE
}
__device__ __forceinline__ float silu_f(float v) { return v / (1.f + __expf(-v)); }

// ---- async global->LDS, 16B per lane ----
__device__ __forceinline__ void async_cp16(unsigned short* lds, const unsigned short* g) {
  __builtin_amdgcn_global_load_lds(
      (const __attribute__((address_space(1))) unsigned int*)g,
      (__attribute__((address_space(3))) unsigned int*)lds, 16, 0, 0);
}

// =================== weight transpose+convert: src[K][N] fp32 -> dst[NP][K] bf16 ===================
__global__ __launch_bounds__(256) void k_wt(const float* __restrict__ src,
                                            unsigned short* __restrict__ dst,
                                            int K, int N, int NP) {
  __shared__ float tile[32][33];
  const int kb = blockIdx.x * 32, nb = blockIdx.y * 32;
  const int tx = threadIdx.x & 31, ty = threadIdx.x >> 5;
#pragma unroll
  for (int i = 0; i < 4; i++) {
    int k = kb + ty + 8 * i, n = nb + tx;
    float v = 0.f;
    if (k < K && n < N) v = src[(size_t)k * N + n];
    tile[ty + 8 * i][tx] = v;
  }
  __syncthreads();
#pragma unroll
  for (int i = 0; i < 4; i++) {
    int n = nb + ty + 8 * i, k = kb + tx;
    if (n < NP && k < K) dst[(size_t)n * K + k] = f2bf(tile[tx][ty + 8 * i]);
  }
}

// =================== mod = silu(c) @ W_ada + b_ada ===================
__global__ __launch_bounds__(256) void k_ada(const float* __restrict__ c,
                                             const float* __restrict__ W,
                                             const float* __restrict__ bias,
                                             float* __restrict__ mod) {
  __shared__ float sc[DM];
  const int b = blockIdx.y, tid = threadIdx.x;
  for (int k = tid; k < DM; k += 256) sc[k] = silu_f(c[b * DM + k]);
  __syncthreads();
  const int j = blockIdx.x * 256 + tid;
  float acc = bias[j];
#pragma unroll 8
  for (int k = 0; k < DM; k++) acc += sc[k] * W[(size_t)k * 3072 + j];
  mod[b * 3072 + j] = acc;
}

// =================== LayerNorm + adaLN modulation -> bf16 ===================
__global__ __launch_bounds__(256) void k_ln(const float* __restrict__ x,
                                            const float* __restrict__ mod,
                                            unsigned short* __restrict__ h) {
  const int row = blockIdx.x, b = row >> 11, tid = threadIdx.x;
  const float4 v = ((const float4*)(x + (size_t)row * DM))[tid];
  float s = v.x + v.y + v.z + v.w;
  float ss = v.x * v.x + v.y * v.y + v.z * v.z + v.w * v.w;
#pragma unroll
  for (int off = 32; off; off >>= 1) { s += __shfl_down(s, off); ss += __shfl_down(ss, off); }
  __shared__ float red[10];
  const int wv = tid >> 6, ln = tid & 63;
  if (ln == 0) { red[wv] = s; red[4 + wv] = ss; }
  __syncthreads();
  if (tid == 0) {
    float st = red[0] + red[1] + red[2] + red[3];
    float sst = red[4] + red[5] + red[6] + red[7];
    float mu = st * (1.f / DM);
    red[8] = mu;
    red[9] = rsqrtf(sst * (1.f / DM) - mu * mu + 1e-6f);
  }
  __syncthreads();
  const float mu = red[8], rstd = red[9];
  const int ccol = tid * 4;
  const float4 sc = *(const float4*)(mod + b * 3072 + ccol);
  const float4 sh = *(const float4*)(mod + b * 3072 + DM + ccol);
  uint2 p;
  p.x = (unsigned)f2bf((v.x - mu) * rstd * (1.f + sc.x) + sh.x) |
        ((unsigned)f2bf((v.y - mu) * rstd * (1.f + sc.y) + sh.y) << 16);
  p.y = (unsigned)f2bf((v.z - mu) * rstd * (1.f + sc.z) + sh.z) |
        ((unsigned)f2bf((v.w - mu) * rstd * (1.f + sc.w) + sh.w) << 16);
  *(uint2*)(h + (size_t)row * DM + ccol) = p;
}

// =================== bf16 MFMA GEMM, 128x128 tile, m97 structure ===================
struct GArgs {
  const unsigned short* A;
  const unsigned short* Bt;
  int lda, ldb, klen;
  float* f0;
  unsigned short* h0;
  unsigned short* h1;
  const float* c0;
  const float* c1;
};

template<int EPI>
__global__ __launch_bounds__(256, 2) void k_gemm(GArgs g) {
  __shared__ unsigned short sA[128 * 32];
  __shared__ unsigned short sB[128 * 32];
  const int tid = threadIdx.x;
  const int w = tid >> 6, lane = tid & 63;
  const int m0 = blockIdx.x * 128, n0 = blockIdx.y * 128;
  const int kstart = blockIdx.z * g.klen;
  const int r4 = lane >> 2;
  const int c8 = (lane & 3) * 8;
  const int rowA0 = w * 16 + r4, rowA1 = (w + 4) * 16 + r4;
  const unsigned short* gA0 = g.A + (size_t)(m0 + rowA0) * g.lda + kstart + c8;
  const unsigned short* gA1 = g.A + (size_t)(m0 + rowA1) * g.lda + kstart + c8;
  const unsigned short* gB0 = g.Bt + (size_t)(n0 + rowA0) * g.ldb + kstart + c8;
  const unsigned short* gB1 = g.Bt + (size_t)(n0 + rowA1) * g.ldb + kstart + c8;
  unsigned short* lA0 = sA + w * 512;
  unsigned short* lA1 = sA + (w + 4) * 512;
  unsigned short* lB0 = sB + w * 512;
  unsigned short* lB1 = sB + (w + 4) * 512;
  const int mw = (w & 1) * 64, nw = (w >> 1) * 64;
  const int row16 = lane & 15, k8 = (lane >> 4) * 8;
  f32x4 acc[4][4] = {};
  for (int kk = 0; kk < g.klen; kk += 32) {
    async_cp16(lA0, gA0); async_cp16(lA1, gA1);
    async_cp16(lB0, gB0); async_cp16(lB1, gB1);
    gA0 += 32; gA1 += 32; gB0 += 32; gB1 += 32;
    __syncthreads();
    bf16x8 av[4], bv[4];
#pragma unroll
    for (int i = 0; i < 4; i++)
      av[i] = *(const bf16x8*)(sA + (mw + 16 * i + row16) * 32 + k8);
#pragma unroll
    for (int j = 0; j < 4; j++)
      bv[j] = *(const bf16x8*)(sB + (nw + 16 * j + row16) * 32 + k8);
#pragma unroll
    for (int i = 0; i < 4; i++)
#pragma unroll
      for (int j = 0; j < 4; j++)
        acc[i][j] = __builtin_amdgcn_mfma_f32_16x16x32_bf16(av[i], bv[j], acc[i][j], 0, 0, 0);
    __syncthreads();
  }
  const int qr = (lane >> 4) * 4, cn = lane & 15;
#pragma unroll
  for (int i = 0; i < 4; i++) {
    const int m = m0 + mw + 16 * i + qr;
    const int b = m >> 11, t = m & 2047;
#pragma unroll
    for (int j = 0; j < 4; j++) {
      const int n = n0 + nw + 16 * j + cn;
      f32x4 v = acc[i][j];
      if constexpr (EPI == 0) {
        uint2 p;
        p.x = (unsigned)f2bf(v[0]) | ((unsigned)f2bf(v[1]) << 16);
        p.y = (unsigned)f2bf(v[2]) | ((unsigned)f2bf(v[3]) << 16);
        unsigned short* dst = (n < DI)
            ? g.h0 + ((size_t)b << 22) + (size_t)n * L_ + t
            : g.h1 + ((size_t)b << 22) + (size_t)(n - DI) * L_ + t;
        *(uint2*)dst = p;
      } else if constexpr (EPI == 1) {
        *(f32x4*)(g.f0 + ((size_t)(blockIdx.z * 128 + n)) * 8192 + m) = v;
      } else if constexpr (EPI == 2) {
        const float bn = g.c0[n];
        f32x4 o;
#pragma unroll
        for (int r = 0; r < 4; r++) {
          float xx = v[r] + bn;
          o[r] = (xx > 15.f) ? xx : __logf(1.f + __expf(xx));
        }
        *(f32x4*)(g.f0 + ((size_t)b << 22) + (size_t)n * L_ + t) = o;
      } else {
        const float gate = g.c1[b * 3072 + 2048 + n];
#pragma unroll
        for (int r = 0; r < 4; r++) {
          size_t idx = (size_t)(m + r) * DM + n;
          g.f0[idx] = g.c0[idx] + gate * v[r];
        }
      }
    }
  }
}

// =================== causal depthwise conv (k=4) + silu ===================
__global__ __launch_bounds__(256) void k_conv(const unsigned short* __restrict__ xmT,
                                              const float* __restrict__ conv_w,
                                              const float* __restrict__ conv_b,
                                              unsigned short* __restrict__ uT,
                                              unsigned short* __restrict__ xc) {
  __shared__ unsigned short sT[32][33];
  const int b = blockIdx.z, t0 = blockIdx.x * 32, d0 = blockIdx.y * 32;
  const int tid = threadIdx.x;
  const int tq = tid & 7, dx = tid >> 3;
  const int d = d0 + dx;
  const int tg = t0 + tq * 4;
  const unsigned short* src = xmT + ((size_t)b << 22) + (size_t)d * L_;
  uint2 wA = make_uint2(0u, 0u);
  if (tg >= 4) wA = *(const uint2*)(src + tg - 4);
  const uint2 wB = *(const uint2*)(src + tg);
  float xw[8];
  xw[0] = bf2f(wA.x); xw[1] = bf2f(wA.x >> 16);
  xw[2] = bf2f(wA.y); xw[3] = bf2f(wA.y >> 16);
  xw[4] = bf2f(wB.x); xw[5] = bf2f(wB.x >> 16);
  xw[6] = bf2f(wB.y); xw[7] = bf2f(wB.y >> 16);
  const float w0 = conv_w[d * 4 + 0], w1 = conv_w[d * 4 + 1];
  const float w2 = conv_w[d * 4 + 2], w3 = conv_w[d * 4 + 3];
  const float cb = conv_b[d];
  unsigned short rb[4];
#pragma unroll
  for (int i = 0; i < 4; i++) {
    float a = cb + w0 * xw[i + 1] + w1 * xw[i + 2] + w2 * xw[i + 3] + w3 * xw[i + 4];
    rb[i] = f2bf(silu_f(a));
  }
  uint2 p;
  p.x = (unsigned)rb[0] | ((unsigned)rb[1] << 16);
  p.y = (unsigned)rb[2] | ((unsigned)rb[3] << 16);
  *(uint2*)(uT + ((size_t)b << 22) + (size_t)d * L_ + tg) = p;
  const int tl0 = tq * 4;
#pragma unroll
  for (int i = 0; i < 4; i++) sT[tl0 + i][dx] = rb[i];
  __syncthreads();
  const int dl2 = tid & 31, tb2 = tid >> 5;
#pragma unroll
  for (int i = 0; i < 4; i++) {
    int tl = tb2 + 8 * i;
    xc[((size_t)b * L_ + t0 + tl) * (size_t)DI + d0 + dl2] = sT[tl][dl2];
  }
}

// =================== reduce split-K partials, split dt / pack BC[b][t][32] ===================
__global__ __launch_bounds__(256) void k_xsplit(const float* __restrict__ pt,
                                                unsigned short* __restrict__ dtb,
                                                float* __restrict__ BC) {
  const int bx = blockIdx.x;
  const int n = bx >> 5;
  const int m = ((bx & 31) << 8) + threadIdx.x;
  float v = pt[(size_t)n * 8192 + m] + pt[(size_t)(128 + n) * 8192 + m] +
            pt[(size_t)(256 + n) * 8192 + m] + pt[(size_t)(384 + n) * 8192 + m];
  if (n < 64) dtb[(size_t)m * 64 + n] = f2bf(v);
  else if (n < 80) BC[(size_t)m * 32 + (n - 64)] = v;
  else BC[(size_t)m * 32 + 16 + (n - 80)] = v;
}

// =================== scan phase A: local chunk scan, emit h_loc[16] + sum(delta) ===================
// thread per (b, d, chunk); grid (DI/256, B, NC-1)
__global__ __launch_bounds__(256, 4) void k_scanA(const float* __restrict__ dT,
                                                  const unsigned short* __restrict__ uT,
                                                  const float* __restrict__ BC,
                                                  const float* __restrict__ A_log,
                                                  float* __restrict__ hloc,
                                                  float* __restrict__ dsum) {
  const int b = blockIdx.y, c = blockIdx.z;
  const int d = blockIdx.x * 256 + threadIdx.x;
  const float* dp = dT + ((size_t)b << 22) + (size_t)d * L_ + c * TC;
  const unsigned short* up = uT + ((size_t)b << 22) + (size_t)d * L_ + c * TC;
  const float* bc = BC + ((size_t)(b * L_ + c * TC)) * 32;
  float As[16];
#pragma unroll
  for (int q = 0; q < 4; q++) {
    const f32x4 av = *(const f32x4*)(A_log + (size_t)d * 16 + q * 4);
#pragma unroll
    for (int j = 0; j < 4; j++) As[q * 4 + j] = -__expf(av[j]);
  }
  float h[16];
#pragma unroll
  for (int s = 0; s < 16; s++) h[s] = 0.f;
  float sd = 0.f;
  for (int t8 = 0; t8 < TC; t8 += 8) {
    const f32x4 dva = *(const f32x4*)(dp + t8);
    const f32x4 dvb = *(const f32x4*)(dp + t8 + 4);
    const uint4 ur = *(const uint4*)(up + t8);
    const float dv[8] = {dva[0], dva[1], dva[2], dva[3], dvb[0], dvb[1], dvb[2], dvb[3]};
    const float uv[8] = {bf2f(ur.x), bf2f(ur.x >> 16), bf2f(ur.y), bf2f(ur.y >> 16),
                         bf2f(ur.z), bf2f(ur.z >> 16), bf2f(ur.w), bf2f(ur.w >> 16)};
#pragma unroll
    for (int i = 0; i < 8; i++) {
      const float dvi = dv[i];
      const float w = dvi * uv[i];
      sd += dvi;
      const float* bct = bc + (size_t)(t8 + i) * 32;
#pragma unroll
      for (int q = 0; q < 4; q++) {
        const f32x4 bq = *(const f32x4*)(bct + q * 4);
#pragma unroll
        for (int j = 0; j < 4; j++) {
          const int s = q * 4 + j;
          const float a = __expf(dvi * As[s]);
          h[s] = a * h[s] + w * bq[j];
        }
      }
    }
  }
  float* hl = hloc + (((size_t)(b * NC + c)) * DI + d) * 16;
#pragma unroll
  for (int q = 0; q < 4; q++) {
    f32x4 v = {h[q * 4], h[q * 4 + 1], h[q * 4 + 2], h[q * 4 + 3]};
    *(f32x4*)(hl + q * 4) = v;
  }
  dsum[((size_t)(b * NC + c)) * DI + d] = sd;
}

// =================== scan phase B: chunk prefix per (b,d) ===================
__global__ __launch_bounds__(256) void k_scanB(const float* __restrict__ hloc,
                                               const float* __restrict__ dsum,
                                               const float* __restrict__ A_log,
                                               float* __restrict__ hin) {
  const int i = blockIdx.x * 256 + threadIdx.x;   // 8192 = B*DI
  const int b = i >> 11, d = i & 2047;
  float As[16];
#pragma unroll
  for (int q = 0; q < 4; q++) {
    const f32x4 av = *(const f32x4*)(A_log + (size_t)d * 16 + q * 4);
#pragma unroll
    for (int j = 0; j < 4; j++) As[q * 4 + j] = -__expf(av[j]);
  }
  float H[16];
#pragma unroll
  for (int s = 0; s < 16; s++) H[s] = 0.f;
  for (int c = 0; c < NC; c++) {
    float* hp = hin + (((size_t)(b * NC + c)) * DI + d) * 16;
#pragma unroll
    for (int q = 0; q < 4; q++) {
      f32x4 v = {H[q * 4], H[q * 4 + 1], H[q * 4 + 2], H[q * 4 + 3]};
      *(f32x4*)(hp + q * 4) = v;
    }
    if (c < NC - 1) {
      const float sd = dsum[((size_t)(b * NC + c)) * DI + d];
      const float* hl = hloc + (((size_t)(b * NC + c)) * DI + d) * 16;
#pragma unroll
      for (int s = 0; s < 16; s++)
        H[s] = __expf(sd * As[s]) * H[s] + hl[s];
    }
  }
}

// =================== scan phase C: apply carry, y = C.h, fused skip + silu(z) gate ===================
// thread per (b, d, chunk); grid (DI/256, B, NC)
__global__ __launch_bounds__(256, 4) void k_scanC(const float* __restrict__ dT,
                                                  const unsigned short* __restrict__ uT,
                                                  const unsigned short* __restrict__ zT,
                                                  const float* __restrict__ BC,
                                                  const float* __restrict__ A_log,
                                                  const float* __restrict__ Dsk,
                                                  const float* __restrict__ hin,
                                                  unsigned short* __restrict__ y) {
  const int b = blockIdx.y, c = blockIdx.z;
  const int d = blockIdx.x * 256 + threadIdx.x;
  const float* dp = dT + ((size_t)b << 22) + (size_t)d * L_ + c * TC;
  const unsigned short* up = uT + ((size_t)b << 22) + (size_t)d * L_ + c * TC;
  const unsigned short* zp = zT + ((size_t)b << 22) + (size_t)d * L_ + c * TC;
  const float* bc = BC + ((size_t)(b * L_ + c * TC)) * 32;
  float As[16];
#pragma unroll
  for (int q = 0; q < 4; q++) {
    const f32x4 av = *(const f32x4*)(A_log + (size_t)d * 16 + q * 4);
#pragma unroll
    for (int j = 0; j < 4; j++) As[q * 4 + j] = -__expf(av[j]);
  }
  const float dsk = Dsk[d];
  float h[16];
  const float* hp = hin + (((size_t)(b * NC + c)) * DI + d) * 16;
#pragma unroll
  for (int q = 0; q < 4; q++) {
    const f32x4 v = *(const f32x4*)(hp + q * 4);
#pragma unroll
    for (int j = 0; j < 4; j++) h[q * 4 + j] = v[j];
  }
  unsigned short* yp = y + ((size_t)(b * L_ + c * TC)) * DI + d;
  for (int t8 = 0; t8 < TC; t8 += 8) {
    const f32x4 dva = *(const f32x4*)(dp + t8);
    const f32x4 dvb = *(const f32x4*)(dp + t8 + 4);
    const uint4 ur = *(const uint4*)(up + t8);
    const uint4 zr = *(const uint4*)(zp + t8);
    const float dv[8] = {dva[0], dva[1], dva[2], dva[3], dvb[0], dvb[1], dvb[2], dvb[3]};
    const float uv[8] = {bf2f(ur.x), bf2f(ur.x >> 16), bf2f(ur.y), bf2f(ur.y >> 16),
                         bf2f(ur.z), bf2f(ur.z >> 16), bf2f(ur.w), bf2f(ur.w >> 16)};
    const float zv[8] = {bf2f(zr.x), bf2f(zr.x >> 16), bf2f(zr.y), bf2f(zr.y >> 16),
                         bf2f(zr.z), bf2f(zr.z >> 16), bf2f(zr.w), bf2f(zr.w >> 16)};
#pragma unroll
    for (int i = 0; i < 8; i++) {
      const float dvi = dv[i];
      const float w = dvi * uv[i];
      const float* bct = bc + (size_t)(t8 + i) * 32;
      float y0 = 0.f, y1 = 0.f;
#pragma unroll
      for (int q = 0; q < 4; q++) {
        const f32x4 bq = *(const f32x4*)(bct + q * 4);
        const f32x4 cq = *(const f32x4*)(bct + 16 + q * 4);
#pragma unroll
        for (int j = 0; j < 4; j++) {
          const int s = q * 4 + j;
          const float a = __expf(dvi * As[s]);
          h[s] = a * h[s] + w * bq[j];
          if (j & 1) y1 += h[s] * cq[j]; else y0 += h[s] * cq[j];
        }
      }
      const float yt = (y0 + y1 + uv[i] * dsk) * silu_f(zv[i]);
      yp[(size_t)(t8 + i) * DI] = f2bf(yt);
    }
  }
}

// =================== launch ===================
extern "C" void kernel_launch(void* const* d_in, const int* in_sizes, int n_in,
                              void* d_out, int out_size, void* d_ws, size_t ws_size,
                              hipStream_t stream) {
  const float* x      = (const float*)d_in[0];
  const float* c      = (const float*)d_in[1];
  const float* W_in   = (const float*)d_in[2];
  const float* conv_w = (const float*)d_in[3];
  const float* conv_b = (const float*)d_in[4];
  const float* W_xp   = (const float*)d_in[5];
  const float* W_dt   = (const float*)d_in[6];
  const float* b_dt   = (const float*)d_in[7];
  const float* A_log  = (const float*)d_in[8];
  const float* D_skip = (const float*)d_in[9];
  const float* W_out  = (const float*)d_in[10];
  const float* W_ada  = (const float*)d_in[11];
  const float* b_ada  = (const float*)d_in[12];
  float* out = (float*)d_out;

  char* ws = (char*)d_ws;
  size_t off = 0;
  auto take = [&](size_t bytes) {
    char* p = ws + off;
    off += (bytes + 255) & ~(size_t)255;
    return p;
  };
  // Footprint same as R1/R3 (known to fit). Scan temporaries alias dead regions.
  float* mod             = (float*)take((size_t)4 * 3072 * 4);
  unsigned short* Wt_in  = (unsigned short*)take((size_t)4096 * 1024 * 2);
  unsigned short* Wt_out = (unsigned short*)take((size_t)1024 * 2048 * 2);
  unsigned short* Wt_xp  = (unsigned short*)take((size_t)128 * 2048 * 2);
  unsigned short* Wt_dt  = (unsigned short*)take((size_t)2048 * 64 * 2);
  unsigned short* h_bf   = (unsigned short*)take((size_t)8192 * 1024 * 2);      // 16MB; reused: part_T, then hin
  unsigned short* xm_T   = (unsigned short*)take((size_t)4 * 2048 * 2048 * 2);  // reused as y_bf
  unsigned short* z_T    = (unsigned short*)take((size_t)4 * 2048 * 2048 * 2);
  unsigned short* u_T    = (unsigned short*)take((size_t)4 * 2048 * 2048 * 2);
  unsigned short* xc     = (unsigned short*)take((size_t)8192 * 2048 * 2);      // 32MB; reused: hloc(16MB)+dsum(1MB)
  float* delta_T         = (float*)take((size_t)4 * 2048 * 2048 * 4);
  unsigned short* dt_bf  = (unsigned short*)take((size_t)8192 * 64 * 2);
  float* BC              = (float*)take((size_t)4 * 2048 * 32 * 4);             // [b][t][32]: B|C packed
  float* part_T = (float*)h_bf;                                  // dead after k_xsplit
  float* hin    = (float*)h_bf;                                  // 16MB exact; written in scanB
  float* hloc   = (float*)xc;                                    // 16MB; written in scanA
  float* dsum   = (float*)(xc + (size_t)8 * 1024 * 1024);        // +16MB offset, 1MB
  unsigned short* y_bf = xm_T;                                   // xm_T dead after conv

  // 1. weight convert+transpose
  k_wt<<<dim3(32, 128), 256, 0, stream>>>(W_in, Wt_in, 1024, 4096, 4096);
  k_wt<<<dim3(64, 32), 256, 0, stream>>>(W_out, Wt_out, 2048, 1024, 1024);
  k_wt<<<dim3(64, 4), 256, 0, stream>>>(W_xp, Wt_xp, 2048, 96, 128);
  k_wt<<<dim3(2, 64), 256, 0, stream>>>(W_dt, Wt_dt, 64, 2048, 2048);
  // 2. conditioning
  k_ada<<<dim3(12, 4), 256, 0, stream>>>(c, W_ada, b_ada, mod);
  // 3. LN + modulation
  k_ln<<<8192, 256, 0, stream>>>(x, mod, h_bf);
  // 4. in-proj
  GArgs a1{h_bf, Wt_in, 1024, 1024, 1024, nullptr, xm_T, z_T, nullptr, nullptr};
  k_gemm<0><<<dim3(64, 32), 256, 0, stream>>>(a1);
  // 5. conv + silu
  k_conv<<<dim3(64, 64, 4), 256, 0, stream>>>(xm_T, conv_w, conv_b, u_T, xc);
  // 6. x-proj (split-K)
  GArgs a2{xc, Wt_xp, 2048, 2048, 512, part_T, nullptr, nullptr, nullptr, nullptr};
  k_gemm<1><<<dim3(64, 1, 4), 256, 0, stream>>>(a2);
  // 7. reduce + split (dt -> bf16 rows; B/C -> BC[b][t][32])
  k_xsplit<<<3072, 256, 0, stream>>>(part_T, dt_bf, BC);
  // 8. dt-proj + softplus
  GArgs a3{dt_bf, Wt_dt, 64, 64, 64, delta_T, nullptr, nullptr, b_dt, nullptr};
  k_gemm<2><<<dim3(64, 16), 256, 0, stream>>>(a3);
  // 9. chunked selective scan, thread-per-(b,d), 16 states in registers
  k_scanA<<<dim3(8, 4, NC - 1), 256, 0, stream>>>(delta_T, u_T, BC, A_log, hloc, dsum);
  k_scanB<<<32, 256, 0, stream>>>(hloc, dsum, A_log, hin);
  k_scanC<<<dim3(8, 4, NC), 256, 0, stream>>>(delta_T, u_T, z_T, BC, A_log, D_skip, hin, y_bf);
  // 10. out-proj + residual + gate
  GArgs a4{y_bf, Wt_out, 2048, 2048, 2048, out, nullptr, nullptr, x, mod};
  k_gemm<3><<<dim3(64, 8), 256, 0, stream>>>(a4);
}

// Round 5
// 600.460 us; speedup vs baseline: 1.5151x; 1.1920x over previous
//
#include <hip/hip_runtime.h>
#include <hip/hip_bf16.h>
#include <stdint.h>

// MambaConditioningBlock on gfx950.
// B=4, L=2048, D_MODEL=1024, D_INNER=2048, D_STATE=16, DT_RANK=64, D_CONV=4.
// R5 change: scan tensors flipped from [b][d][t] to [m][d] (m=b*L+t).
// R4's scanC fetched 421MB vs 145MB ideal (lane-stride-8KB loads thrashed
// partially-consumed lines). [m][d] makes every scan load/store wave-dense.
// Bonus: u==xc (one buffer, conv loses transpose+2nd output), gemm<0>/<2>
// epilogues store naturally. hloc/dsum live in freed u_T slot; ws unchanged.

#define L_ 2048
#define DM 1024
#define DI 2048
#define DS 16
#define NC 32    // scan chunks
#define TC 64    // steps per chunk

typedef __bf16 bf16x8 __attribute__((ext_vector_type(8)));
typedef float f32x4 __attribute__((ext_vector_type(4)));

__device__ __forceinline__ float bf2f(unsigned int u) {
  union { unsigned int i; float f; } c;
  c.i = (u & 0xFFFFu) << 16;
  return c.f;
}
__device__ __forceinline__ unsigned short f2bf(float f) {
  union { float f; unsigned int i; } c; c.f = f;
  unsigned int x = c.i;
  return (unsigned short)((x + 0x7FFFu + ((x >> 16) & 1u)) >> 16);  // RNE
}
__device__ __forceinline__ float silu_f(float v) { return v / (1.f + __expf(-v)); }

// ---- async global->LDS, 16B per lane ----
__device__ __forceinline__ void async_cp16(unsigned short* lds, const unsigned short* g) {
  __builtin_amdgcn_global_load_lds(
      (const __attribute__((address_space(1))) unsigned int*)g,
      (__attribute__((address_space(3))) unsigned int*)lds, 16, 0, 0);
}

// =================== weight transpose+convert: src[K][N] fp32 -> dst[NP][K] bf16 ===================
__global__ __launch_bounds__(256) void k_wt(const float* __restrict__ src,
                                            unsigned short* __restrict__ dst,
                                            int K, int N, int NP) {
  __shared__ float tile[32][33];
  const int kb = blockIdx.x * 32, nb = blockIdx.y * 32;
  const int tx = threadIdx.x & 31, ty = threadIdx.x >> 5;
#pragma unroll
  for (int i = 0; i < 4; i++) {
    int k = kb + ty + 8 * i, n = nb + tx;
    float v = 0.f;
    if (k < K && n < N) v = src[(size_t)k * N + n];
    tile[ty + 8 * i][tx] = v;
  }
  __syncthreads();
#pragma unroll
  for (int i = 0; i < 4; i++) {
    int n = nb + ty + 8 * i, k = kb + tx;
    if (n < NP && k < K) dst[(size_t)n * K + k] = f2bf(tile[tx][ty + 8 * i]);
  }
}

// =================== mod = silu(c) @ W_ada + b_ada ===================
__global__ __launch_bounds__(256) void k_ada(const float* __restrict__ c,
                                             const float* __restrict__ W,
                                             const float* __restrict__ bias,
                                             float* __restrict__ mod) {
  __shared__ float sc[DM];
  const int b = blockIdx.y, tid = threadIdx.x;
  for (int k = tid; k < DM; k += 256) sc[k] = silu_f(c[b * DM + k]);
  __syncthreads();
  const int j = blockIdx.x * 256 + tid;
  float acc = bias[j];
#pragma unroll 8
  for (int k = 0; k < DM; k++) acc += sc[k] * W[(size_t)k * 3072 + j];
  mod[b * 3072 + j] = acc;
}

// =================== LayerNorm + adaLN modulation -> bf16 ===================
__global__ __launch_bounds__(256) void k_ln(const float* __restrict__ x,
                                            const float* __restrict__ mod,
                                            unsigned short* __restrict__ h) {
  const int row = blockIdx.x, b = row >> 11, tid = threadIdx.x;
  const float4 v = ((const float4*)(x + (size_t)row * DM))[tid];
  float s = v.x + v.y + v.z + v.w;
  float ss = v.x * v.x + v.y * v.y + v.z * v.z + v.w * v.w;
#pragma unroll
  for (int off = 32; off; off >>= 1) { s += __shfl_down(s, off); ss += __shfl_down(ss, off); }
  __shared__ float red[10];
  const int wv = tid >> 6, ln = tid & 63;
  if (ln == 0) { red[wv] = s; red[4 + wv] = ss; }
  __syncthreads();
  if (tid == 0) {
    float st = red[0] + red[1] + red[2] + red[3];
    float sst = red[4] + red[5] + red[6] + red[7];
    float mu = st * (1.f / DM);
    red[8] = mu;
    red[9] = rsqrtf(sst * (1.f / DM) - mu * mu + 1e-6f);
  }
  __syncthreads();
  const float mu = red[8], rstd = red[9];
  const int ccol = tid * 4;
  const float4 sc = *(const float4*)(mod + b * 3072 + ccol);
  const float4 sh = *(const float4*)(mod + b * 3072 + DM + ccol);
  uint2 p;
  p.x = (unsigned)f2bf((v.x - mu) * rstd * (1.f + sc.x) + sh.x) |
        ((unsigned)f2bf((v.y - mu) * rstd * (1.f + sc.y) + sh.y) << 16);
  p.y = (unsigned)f2bf((v.z - mu) * rstd * (1.f + sc.z) + sh.z) |
        ((unsigned)f2bf((v.w - mu) * rstd * (1.f + sc.w) + sh.w) << 16);
  *(uint2*)(h + (size_t)row * DM + ccol) = p;
}

// =================== bf16 MFMA GEMM, 128x128 tile, m97 structure ===================
struct GArgs {
  const unsigned short* A;
  const unsigned short* Bt;
  int lda, ldb, klen;
  float* f0;
  unsigned short* h0;
  unsigned short* h1;
  const float* c0;
  const float* c1;
};

template<int EPI>
__global__ __launch_bounds__(256, 2) void k_gemm(GArgs g) {
  __shared__ unsigned short sA[128 * 32];
  __shared__ unsigned short sB[128 * 32];
  const int tid = threadIdx.x;
  const int w = tid >> 6, lane = tid & 63;
  const int m0 = blockIdx.x * 128, n0 = blockIdx.y * 128;
  const int kstart = blockIdx.z * g.klen;
  const int r4 = lane >> 2;
  const int c8 = (lane & 3) * 8;
  const int rowA0 = w * 16 + r4, rowA1 = (w + 4) * 16 + r4;
  const unsigned short* gA0 = g.A + (size_t)(m0 + rowA0) * g.lda + kstart + c8;
  const unsigned short* gA1 = g.A + (size_t)(m0 + rowA1) * g.lda + kstart + c8;
  const unsigned short* gB0 = g.Bt + (size_t)(n0 + rowA0) * g.ldb + kstart + c8;
  const unsigned short* gB1 = g.Bt + (size_t)(n0 + rowA1) * g.ldb + kstart + c8;
  unsigned short* lA0 = sA + w * 512;
  unsigned short* lA1 = sA + (w + 4) * 512;
  unsigned short* lB0 = sB + w * 512;
  unsigned short* lB1 = sB + (w + 4) * 512;
  const int mw = (w & 1) * 64, nw = (w >> 1) * 64;
  const int row16 = lane & 15, k8 = (lane >> 4) * 8;
  f32x4 acc[4][4] = {};
  for (int kk = 0; kk < g.klen; kk += 32) {
    async_cp16(lA0, gA0); async_cp16(lA1, gA1);
    async_cp16(lB0, gB0); async_cp16(lB1, gB1);
    gA0 += 32; gA1 += 32; gB0 += 32; gB1 += 32;
    __syncthreads();
    bf16x8 av[4], bv[4];
#pragma unroll
    for (int i = 0; i < 4; i++)
      av[i] = *(const bf16x8*)(sA + (mw + 16 * i + row16) * 32 + k8);
#pragma unroll
    for (int j = 0; j < 4; j++)
      bv[j] = *(const bf16x8*)(sB + (nw + 16 * j + row16) * 32 + k8);
#pragma unroll
    for (int i = 0; i < 4; i++)
#pragma unroll
      for (int j = 0; j < 4; j++)
        acc[i][j] = __builtin_amdgcn_mfma_f32_16x16x32_bf16(av[i], bv[j], acc[i][j], 0, 0, 0);
    __syncthreads();
  }
  const int qr = (lane >> 4) * 4, cn = lane & 15;
#pragma unroll
  for (int i = 0; i < 4; i++) {
    const int m = m0 + mw + 16 * i + qr;
    const int b = m >> 11;
#pragma unroll
    for (int j = 0; j < 4; j++) {
      const int n = n0 + nw + 16 * j + cn;
      f32x4 v = acc[i][j];
      if constexpr (EPI == 0) {
        // in-proj: natural [m][d] stores; split xm / z
#pragma unroll
        for (int r = 0; r < 4; r++) {
          unsigned short* dst = (n < DI)
              ? g.h0 + (size_t)(m + r) * DI + n
              : g.h1 + (size_t)(m + r) * DI + (n - DI);
          *dst = f2bf(v[r]);
        }
      } else if constexpr (EPI == 1) {
        // x-proj split-K partial, transposed [z][n][m] fp32
        *(f32x4*)(g.f0 + ((size_t)(blockIdx.z * 128 + n)) * 8192 + m) = v;
      } else if constexpr (EPI == 2) {
        // dt-proj: +b_dt, softplus, natural [m][d] fp32
        const float bn = g.c0[n];
#pragma unroll
        for (int r = 0; r < 4; r++) {
          float xx = v[r] + bn;
          g.f0[(size_t)(m + r) * DI + n] = (xx > 15.f) ? xx : __logf(1.f + __expf(xx));
        }
      } else {
        // out-proj: out = x + gate * acc
        const float gate = g.c1[b * 3072 + 2048 + n];
#pragma unroll
        for (int r = 0; r < 4; r++) {
          size_t idx = (size_t)(m + r) * DM + n;
          g.f0[idx] = g.c0[idx] + gate * v[r];
        }
      }
    }
  }
}

// =================== causal depthwise conv (k=4) + silu, [m][d] -> [m][d] ===================
// thread: one t, 8 consecutive d. grid (L/32, DI/64, B), block 256 = 32t x 8dgrp.
__global__ __launch_bounds__(256) void k_conv(const unsigned short* __restrict__ xm,
                                              const float* __restrict__ conv_w,
                                              const float* __restrict__ conv_b,
                                              unsigned short* __restrict__ u) {
  const int b = blockIdx.z;
  const int t = blockIdx.x * 32 + (threadIdx.x >> 3);
  const int d = blockIdx.y * 64 + (threadIdx.x & 7) * 8;
  const size_t rowbase = ((size_t)(b * L_ + t)) * DI + d;
  uint4 r3 = *(const uint4*)(xm + rowbase);
  uint4 r0 = make_uint4(0, 0, 0, 0), r1 = r0, r2 = r0;
  if (t >= 3) r0 = *(const uint4*)(xm + rowbase - 3 * DI);
  if (t >= 2) r1 = *(const uint4*)(xm + rowbase - 2 * DI);
  if (t >= 1) r2 = *(const uint4*)(xm + rowbase - 1 * DI);
  float x0[8], x1[8], x2[8], x3[8];
  const unsigned* p0 = (const unsigned*)&r0;
  const unsigned* p1 = (const unsigned*)&r1;
  const unsigned* p2 = (const unsigned*)&r2;
  const unsigned* p3 = (const unsigned*)&r3;
#pragma unroll
  for (int q = 0; q < 4; q++) {
    x0[2 * q] = bf2f(p0[q]); x0[2 * q + 1] = bf2f(p0[q] >> 16);
    x1[2 * q] = bf2f(p1[q]); x1[2 * q + 1] = bf2f(p1[q] >> 16);
    x2[2 * q] = bf2f(p2[q]); x2[2 * q + 1] = bf2f(p2[q] >> 16);
    x3[2 * q] = bf2f(p3[q]); x3[2 * q + 1] = bf2f(p3[q] >> 16);
  }
  const f32x4 cb0 = *(const f32x4*)(conv_b + d);
  const f32x4 cb1 = *(const f32x4*)(conv_b + d + 4);
  unsigned out[4];
#pragma unroll
  for (int j = 0; j < 8; j++) {
    const f32x4 wj = *(const f32x4*)(conv_w + (size_t)(d + j) * 4);
    const float cb = (j < 4) ? cb0[j] : cb1[j - 4];
    float a = cb + wj[0] * x0[j] + wj[1] * x1[j] + wj[2] * x2[j] + wj[3] * x3[j];
    unsigned short us = f2bf(silu_f(a));
    if (j & 1) out[j >> 1] |= ((unsigned)us << 16);
    else out[j >> 1] = us;
  }
  *(uint4*)(u + rowbase) = make_uint4(out[0], out[1], out[2], out[3]);
}

// =================== reduce split-K partials, split dt / pack BC[m][32] ===================
__global__ __launch_bounds__(256) void k_xsplit(const float* __restrict__ pt,
                                                unsigned short* __restrict__ dtb,
                                                float* __restrict__ BC) {
  const int bx = blockIdx.x;
  const int n = bx >> 5;
  const int m = ((bx & 31) << 8) + threadIdx.x;
  float v = pt[(size_t)n * 8192 + m] + pt[(size_t)(128 + n) * 8192 + m] +
            pt[(size_t)(256 + n) * 8192 + m] + pt[(size_t)(384 + n) * 8192 + m];
  if (n < 64) dtb[(size_t)m * 64 + n] = f2bf(v);
  else if (n < 80) BC[(size_t)m * 32 + (n - 64)] = v;
  else BC[(size_t)m * 32 + 16 + (n - 80)] = v;
}

// =================== scan phase A: local chunk scan, emit h_loc[16] + sum(delta) ===================
// thread per (b, d, chunk); grid (DI/256, B, NC-1). All tensors [m][d].
__global__ __launch_bounds__(256, 4) void k_scanA(const float* __restrict__ delta,
                                                  const unsigned short* __restrict__ u,
                                                  const float* __restrict__ BC,
                                                  const float* __restrict__ A_log,
                                                  float* __restrict__ hloc,
                                                  float* __restrict__ dsum) {
  const int b = blockIdx.y, c = blockIdx.z;
  const int d = blockIdx.x * 256 + threadIdx.x;
  const size_t mbase = (size_t)(b * L_ + c * TC);
  const float* dp = delta + mbase * DI + d;
  const unsigned short* up = u + mbase * DI + d;
  const float* bc = BC + mbase * 32;
  float As[16];
#pragma unroll
  for (int q = 0; q < 4; q++) {
    const f32x4 av = *(const f32x4*)(A_log + (size_t)d * 16 + q * 4);
#pragma unroll
    for (int j = 0; j < 4; j++) As[q * 4 + j] = -__expf(av[j]);
  }
  float h[16];
#pragma unroll
  for (int s = 0; s < 16; s++) h[s] = 0.f;
  float sd = 0.f;
  for (int t8 = 0; t8 < TC; t8 += 8) {
    float dv[8], uvf[8];
#pragma unroll
    for (int i = 0; i < 8; i++) dv[i] = dp[(size_t)(t8 + i) * DI];
#pragma unroll
    for (int i = 0; i < 8; i++) uvf[i] = bf2f(up[(size_t)(t8 + i) * DI]);
#pragma unroll
    for (int i = 0; i < 8; i++) {
      const float dvi = dv[i];
      const float w = dvi * uvf[i];
      sd += dvi;
      const float* bct = bc + (size_t)(t8 + i) * 32;
#pragma unroll
      for (int q = 0; q < 4; q++) {
        const f32x4 bq = *(const f32x4*)(bct + q * 4);
#pragma unroll
        for (int j = 0; j < 4; j++) {
          const int s = q * 4 + j;
          const float a = __expf(dvi * As[s]);
          h[s] = a * h[s] + w * bq[j];
        }
      }
    }
  }
  float* hl = hloc + (((size_t)(b * NC + c)) * DI + d) * 16;
#pragma unroll
  for (int q = 0; q < 4; q++) {
    f32x4 v = {h[q * 4], h[q * 4 + 1], h[q * 4 + 2], h[q * 4 + 3]};
    *(f32x4*)(hl + q * 4) = v;
  }
  dsum[((size_t)(b * NC + c)) * DI + d] = sd;
}

// =================== scan phase B: chunk prefix per (b,d) ===================
__global__ __launch_bounds__(256) void k_scanB(const float* __restrict__ hloc,
                                               const float* __restrict__ dsum,
                                               const float* __restrict__ A_log,
                                               float* __restrict__ hin) {
  const int i = blockIdx.x * 256 + threadIdx.x;   // 8192 = B*DI
  const int b = i >> 11, d = i & 2047;
  float As[16];
#pragma unroll
  for (int q = 0; q < 4; q++) {
    const f32x4 av = *(const f32x4*)(A_log + (size_t)d * 16 + q * 4);
#pragma unroll
    for (int j = 0; j < 4; j++) As[q * 4 + j] = -__expf(av[j]);
  }
  float H[16];
#pragma unroll
  for (int s = 0; s < 16; s++) H[s] = 0.f;
  for (int c = 0; c < NC; c++) {
    float* hp = hin + (((size_t)(b * NC + c)) * DI + d) * 16;
#pragma unroll
    for (int q = 0; q < 4; q++) {
      f32x4 v = {H[q * 4], H[q * 4 + 1], H[q * 4 + 2], H[q * 4 + 3]};
      *(f32x4*)(hp + q * 4) = v;
    }
    if (c < NC - 1) {
      const float sd = dsum[((size_t)(b * NC + c)) * DI + d];
      const float* hl = hloc + (((size_t)(b * NC + c)) * DI + d) * 16;
#pragma unroll
      for (int s = 0; s < 16; s++)
        H[s] = __expf(sd * As[s]) * H[s] + hl[s];
    }
  }
}

// =================== scan phase C: apply carry, y = C.h, fused skip + silu(z) gate ===================
// thread per (b, d, chunk); grid (DI/256, B, NC). All tensors [m][d].
__global__ __launch_bounds__(256, 4) void k_scanC(const float* __restrict__ delta,
                                                  const unsigned short* __restrict__ u,
                                                  const unsigned short* __restrict__ z,
                                                  const float* __restrict__ BC,
                                                  const float* __restrict__ A_log,
                                                  const float* __restrict__ Dsk,
                                                  const float* __restrict__ hin,
                                                  unsigned short* __restrict__ y) {
  const int b = blockIdx.y, c = blockIdx.z;
  const int d = blockIdx.x * 256 + threadIdx.x;
  const size_t mbase = (size_t)(b * L_ + c * TC);
  const float* dp = delta + mbase * DI + d;
  const unsigned short* up = u + mbase * DI + d;
  const unsigned short* zp = z + mbase * DI + d;
  const float* bc = BC + mbase * 32;
  float As[16];
#pragma unroll
  for (int q = 0; q < 4; q++) {
    const f32x4 av = *(const f32x4*)(A_log + (size_t)d * 16 + q * 4);
#pragma unroll
    for (int j = 0; j < 4; j++) As[q * 4 + j] = -__expf(av[j]);
  }
  const float dsk = Dsk[d];
  float h[16];
  const float* hp = hin + (((size_t)(b * NC + c)) * DI + d) * 16;
#pragma unroll
  for (int q = 0; q < 4; q++) {
    const f32x4 v = *(const f32x4*)(hp + q * 4);
#pragma unroll
    for (int j = 0; j < 4; j++) h[q * 4 + j] = v[j];
  }
  unsigned short* yp = y + mbase * DI + d;
  for (int t8 = 0; t8 < TC; t8 += 8) {
    float dv[8], uvf[8], zvf[8];
#pragma unroll
    for (int i = 0; i < 8; i++) dv[i] = dp[(size_t)(t8 + i) * DI];
#pragma unroll
    for (int i = 0; i < 8; i++) uvf[i] = bf2f(up[(size_t)(t8 + i) * DI]);
#pragma unroll
    for (int i = 0; i < 8; i++) zvf[i] = bf2f(zp[(size_t)(t8 + i) * DI]);
#pragma unroll
    for (int i = 0; i < 8; i++) {
      const float dvi = dv[i];
      const float w = dvi * uvf[i];
      const float* bct = bc + (size_t)(t8 + i) * 32;
      float y0 = 0.f, y1 = 0.f;
#pragma unroll
      for (int q = 0; q < 4; q++) {
        const f32x4 bq = *(const f32x4*)(bct + q * 4);
        const f32x4 cq = *(const f32x4*)(bct + 16 + q * 4);
#pragma unroll
        for (int j = 0; j < 4; j++) {
          const int s = q * 4 + j;
          const float a = __expf(dvi * As[s]);
          h[s] = a * h[s] + w * bq[j];
          if (j & 1) y1 += h[s] * cq[j]; else y0 += h[s] * cq[j];
        }
      }
      const float yt = (y0 + y1 + uvf[i] * dsk) * silu_f(zvf[i]);
      yp[(size_t)(t8 + i) * DI] = f2bf(yt);
    }
  }
}

// =================== launch ===================
extern "C" void kernel_launch(void* const* d_in, const int* in_sizes, int n_in,
                              void* d_out, int out_size, void* d_ws, size_t ws_size,
                              hipStream_t stream) {
  const float* x      = (const float*)d_in[0];
  const float* c      = (const float*)d_in[1];
  const float* W_in   = (const float*)d_in[2];
  const float* conv_w = (const float*)d_in[3];
  const float* conv_b = (const float*)d_in[4];
  const float* W_xp   = (const float*)d_in[5];
  const float* W_dt   = (const float*)d_in[6];
  const float* b_dt   = (const float*)d_in[7];
  const float* A_log  = (const float*)d_in[8];
  const float* D_skip = (const float*)d_in[9];
  const float* W_out  = (const float*)d_in[10];
  const float* W_ada  = (const float*)d_in[11];
  const float* b_ada  = (const float*)d_in[12];
  float* out = (float*)d_out;

  char* ws = (char*)d_ws;
  size_t off = 0;
  auto take = [&](size_t bytes) {
    char* p = ws + off;
    off += (bytes + 255) & ~(size_t)255;
    return p;
  };
  // take() sequence identical to R4 (fits ws_size). Aliases noted per-slot.
  float* mod             = (float*)take((size_t)4 * 3072 * 4);
  unsigned short* Wt_in  = (unsigned short*)take((size_t)4096 * 1024 * 2);
  unsigned short* Wt_out = (unsigned short*)take((size_t)1024 * 2048 * 2);
  unsigned short* Wt_xp  = (unsigned short*)take((size_t)128 * 2048 * 2);
  unsigned short* Wt_dt  = (unsigned short*)take((size_t)2048 * 64 * 2);
  unsigned short* h_bf   = (unsigned short*)take((size_t)8192 * 1024 * 2);      // 16MB; then part_T, then hin
  unsigned short* xm     = (unsigned short*)take((size_t)4 * 2048 * 2048 * 2);  // 32MB [m][d]; then y_bf
  unsigned short* z_bf   = (unsigned short*)take((size_t)4 * 2048 * 2048 * 2);  // 32MB [m][d]
  unsigned short* scanws = (unsigned short*)take((size_t)4 * 2048 * 2048 * 2);  // 32MB; hloc(16MB)+dsum(1MB)
  unsigned short* u_bf   = (unsigned short*)take((size_t)8192 * 2048 * 2);      // 32MB [m][d]; u==xc, live thru scanC
  float* delta           = (float*)take((size_t)4 * 2048 * 2048 * 4);           // 64MB [m][d] fp32
  unsigned short* dt_bf  = (unsigned short*)take((size_t)8192 * 64 * 2);
  float* BC              = (float*)take((size_t)4 * 2048 * 32 * 4);             // [m][32]: B|C packed
  float* part_T = (float*)h_bf;                                   // dead after k_xsplit
  float* hin    = (float*)h_bf;                                   // 16MB exact; written by scanB
  float* hloc   = (float*)scanws;                                 // 16MB
  float* dsum   = (float*)(scanws + (size_t)8 * 1024 * 1024);     // +16MB, 1MB
  unsigned short* y_bf = xm;                                      // xm dead after conv

  // 1. weight convert+transpose
  k_wt<<<dim3(32, 128), 256, 0, stream>>>(W_in, Wt_in, 1024, 4096, 4096);
  k_wt<<<dim3(64, 32), 256, 0, stream>>>(W_out, Wt_out, 2048, 1024, 1024);
  k_wt<<<dim3(64, 4), 256, 0, stream>>>(W_xp, Wt_xp, 2048, 96, 128);
  k_wt<<<dim3(2, 64), 256, 0, stream>>>(W_dt, Wt_dt, 64, 2048, 2048);
  // 2. conditioning
  k_ada<<<dim3(12, 4), 256, 0, stream>>>(c, W_ada, b_ada, mod);
  // 3. LN + modulation
  k_ln<<<8192, 256, 0, stream>>>(x, mod, h_bf);
  // 4. in-proj -> xm[m][d], z[m][d]
  GArgs a1{h_bf, Wt_in, 1024, 1024, 1024, nullptr, xm, z_bf, nullptr, nullptr};
  k_gemm<0><<<dim3(64, 32), 256, 0, stream>>>(a1);
  // 5. conv + silu -> u[m][d] (== xc, feeds both x-proj and scan)
  k_conv<<<dim3(64, 32, 4), 256, 0, stream>>>(xm, conv_w, conv_b, u_bf);
  // 6. x-proj (split-K)
  GArgs a2{u_bf, Wt_xp, 2048, 2048, 512, part_T, nullptr, nullptr, nullptr, nullptr};
  k_gemm<1><<<dim3(64, 1, 4), 256, 0, stream>>>(a2);
  // 7. reduce + split (dt rows; BC[m][32])
  k_xsplit<<<3072, 256, 0, stream>>>(part_T, dt_bf, BC);
  // 8. dt-proj + softplus -> delta[m][d] fp32
  GArgs a3{dt_bf, Wt_dt, 64, 64, 64, delta, nullptr, nullptr, b_dt, nullptr};
  k_gemm<2><<<dim3(64, 16), 256, 0, stream>>>(a3);
  // 9. chunked selective scan, [m][d] coalesced
  k_scanA<<<dim3(8, 4, NC - 1), 256, 0, stream>>>(delta, u_bf, BC, A_log, hloc, dsum);
  k_scanB<<<32, 256, 0, stream>>>(hloc, dsum, A_log, hin);
  k_scanC<<<dim3(8, 4, NC), 256, 0, stream>>>(delta, u_bf, z_bf, BC, A_log, D_skip, hin, y_bf);
  // 10. out-proj + residual + gate
  GArgs a4{y_bf, Wt_out, 2048, 2048, 2048, out, nullptr, nullptr, x, mod};
  k_gemm<3><<<dim3(64, 8), 256, 0, stream>>>(a4);
}

// Round 7
// 587.515 us; speedup vs baseline: 1.5484x; 1.0220x over previous
//
#include <hip/hip_runtime.h>
#include <hip/hip_bf16.h>
#include <stdint.h>

// MambaConditioningBlock on gfx950.
// B=4, L=2048, D_MODEL=1024, D_INNER=2048, D_STATE=16, DT_RANK=64, D_CONV=4.
// R7: revert R6's LDS XOR swizzle (crash suspect AND provably ineffective:
// segment-level XOR can't reduce 8-addresses-per-4-bank-group in a 16x64B
// chunk; m97 carries the same conflicts at 874 TF). Keep R6's safe wins:
// delta stored bf16 (-95MB HBM) and fused k_wt4 (3 fewer launch gaps).
// GEMM staging/read indices restored byte-for-byte to R5's proven form.

#define L_ 2048
#define DM 1024
#define DI 2048
#define DS 16
#define NC 32    // scan chunks
#define TC 64    // steps per chunk

typedef __bf16 bf16x8 __attribute__((ext_vector_type(8)));
typedef float f32x4 __attribute__((ext_vector_type(4)));

__device__ __forceinline__ float bf2f(unsigned int u) {
  union { unsigned int i; float f; } c;
  c.i = (u & 0xFFFFu) << 16;
  return c.f;
}
__device__ __forceinline__ unsigned short f2bf(float f) {
  union { float f; unsigned int i; } c; c.f = f;
  unsigned int x = c.i;
  return (unsigned short)((x + 0x7FFFu + ((x >> 16) & 1u)) >> 16);  // RNE
}
__device__ __forceinline__ float silu_f(float v) { return v / (1.f + __expf(-v)); }

// ---- async global->LDS, 16B per lane ----
__device__ __forceinline__ void async_cp16(unsigned short* lds, const unsigned short* g) {
  __builtin_amdgcn_global_load_lds(
      (const __attribute__((address_space(1))) unsigned int*)g,
      (__attribute__((address_space(3))) unsigned int*)lds, 16, 0, 0);
}

// =================== fused weight transpose+convert (4 jobs, flat grid) ===================
// src[K][N] fp32 -> dst[NP][K] bf16 (rows N..NP-1 zero-padded)
__global__ __launch_bounds__(256) void k_wt4(const float* __restrict__ s0, unsigned short* __restrict__ d0,
                                             const float* __restrict__ s1, unsigned short* __restrict__ d1,
                                             const float* __restrict__ s2, unsigned short* __restrict__ d2,
                                             const float* __restrict__ s3, unsigned short* __restrict__ d3) {
  int bid = blockIdx.x;
  const float* src; unsigned short* dst; int K, N, NP, kb, nb;
  if (bid < 4096)                { src = s0; dst = d0; K = 1024; N = 4096; NP = 4096; kb = bid & 31; nb = bid >> 5; }
  else if ((bid -= 4096) < 2048) { src = s1; dst = d1; K = 2048; N = 1024; NP = 1024; kb = bid & 63; nb = bid >> 6; }
  else if ((bid -= 2048) < 256)  { src = s2; dst = d2; K = 2048; N = 96;   NP = 128;  kb = bid & 63; nb = bid >> 6; }
  else { bid -= 256;               src = s3; dst = d3; K = 64;   N = 2048; NP = 2048; kb = bid & 1;  nb = bid >> 1; }
  __shared__ float tile[32][33];
  const int kb0 = kb * 32, nb0 = nb * 32;
  const int tx = threadIdx.x & 31, ty = threadIdx.x >> 5;
#pragma unroll
  for (int i = 0; i < 4; i++) {
    int k = kb0 + ty + 8 * i, n = nb0 + tx;
    float v = 0.f;
    if (k < K && n < N) v = src[(size_t)k * N + n];
    tile[ty + 8 * i][tx] = v;
  }
  __syncthreads();
#pragma unroll
  for (int i = 0; i < 4; i++) {
    int n = nb0 + ty + 8 * i, k = kb0 + tx;
    if (n < NP && k < K) dst[(size_t)n * K + k] = f2bf(tile[tx][ty + 8 * i]);
  }
}

// =================== mod = silu(c) @ W_ada + b_ada ===================
__global__ __launch_bounds__(256) void k_ada(const float* __restrict__ c,
                                             const float* __restrict__ W,
                                             const float* __restrict__ bias,
                                             float* __restrict__ mod) {
  __shared__ float sc[DM];
  const int b = blockIdx.y, tid = threadIdx.x;
  for (int k = tid; k < DM; k += 256) sc[k] = silu_f(c[b * DM + k]);
  __syncthreads();
  const int j = blockIdx.x * 256 + tid;
  float acc = bias[j];
#pragma unroll 8
  for (int k = 0; k < DM; k++) acc += sc[k] * W[(size_t)k * 3072 + j];
  mod[b * 3072 + j] = acc;
}

// =================== LayerNorm + adaLN modulation -> bf16 ===================
__global__ __launch_bounds__(256) void k_ln(const float* __restrict__ x,
                                            const float* __restrict__ mod,
                                            unsigned short* __restrict__ h) {
  const int row = blockIdx.x, b = row >> 11, tid = threadIdx.x;
  const float4 v = ((const float4*)(x + (size_t)row * DM))[tid];
  float s = v.x + v.y + v.z + v.w;
  float ss = v.x * v.x + v.y * v.y + v.z * v.z + v.w * v.w;
#pragma unroll
  for (int off = 32; off; off >>= 1) { s += __shfl_down(s, off); ss += __shfl_down(ss, off); }
  __shared__ float red[10];
  const int wv = tid >> 6, ln = tid & 63;
  if (ln == 0) { red[wv] = s; red[4 + wv] = ss; }
  __syncthreads();
  if (tid == 0) {
    float st = red[0] + red[1] + red[2] + red[3];
    float sst = red[4] + red[5] + red[6] + red[7];
    float mu = st * (1.f / DM);
    red[8] = mu;
    red[9] = rsqrtf(sst * (1.f / DM) - mu * mu + 1e-6f);
  }
  __syncthreads();
  const float mu = red[8], rstd = red[9];
  const int ccol = tid * 4;
  const float4 sc = *(const float4*)(mod + b * 3072 + ccol);
  const float4 sh = *(const float4*)(mod + b * 3072 + DM + ccol);
  uint2 p;
  p.x = (unsigned)f2bf((v.x - mu) * rstd * (1.f + sc.x) + sh.x) |
        ((unsigned)f2bf((v.y - mu) * rstd * (1.f + sc.y) + sh.y) << 16);
  p.y = (unsigned)f2bf((v.z - mu) * rstd * (1.f + sc.z) + sh.z) |
        ((unsigned)f2bf((v.w - mu) * rstd * (1.f + sc.w) + sh.w) << 16);
  *(uint2*)(h + (size_t)row * DM + ccol) = p;
}

// =================== bf16 MFMA GEMM, 128x128 tile, m97 structure ===================
struct GArgs {
  const unsigned short* A;
  const unsigned short* Bt;
  int lda, ldb, klen;
  float* f0;
  unsigned short* h0;
  unsigned short* h1;
  const float* c0;
  const float* c1;
};

template<int EPI>
__global__ __launch_bounds__(256, 2) void k_gemm(GArgs g) {
  __shared__ unsigned short sA[128 * 32];
  __shared__ unsigned short sB[128 * 32];
  const int tid = threadIdx.x;
  const int w = tid >> 6, lane = tid & 63;
  const int m0 = blockIdx.x * 128, n0 = blockIdx.y * 128;
  const int kstart = blockIdx.z * g.klen;
  const int r4 = lane >> 2;
  const int c8 = (lane & 3) * 8;
  const int rowA0 = w * 16 + r4, rowA1 = (w + 4) * 16 + r4;
  const unsigned short* gA0 = g.A + (size_t)(m0 + rowA0) * g.lda + kstart + c8;
  const unsigned short* gA1 = g.A + (size_t)(m0 + rowA1) * g.lda + kstart + c8;
  const unsigned short* gB0 = g.Bt + (size_t)(n0 + rowA0) * g.ldb + kstart + c8;
  const unsigned short* gB1 = g.Bt + (size_t)(n0 + rowA1) * g.ldb + kstart + c8;
  unsigned short* lA0 = sA + w * 512;
  unsigned short* lA1 = sA + (w + 4) * 512;
  unsigned short* lB0 = sB + w * 512;
  unsigned short* lB1 = sB + (w + 4) * 512;
  const int mw = (w & 1) * 64, nw = (w >> 1) * 64;
  const int row16 = lane & 15, k8 = (lane >> 4) * 8;
  f32x4 acc[4][4] = {};
  for (int kk = 0; kk < g.klen; kk += 32) {
    async_cp16(lA0, gA0); async_cp16(lA1, gA1);
    async_cp16(lB0, gB0); async_cp16(lB1, gB1);
    gA0 += 32; gA1 += 32; gB0 += 32; gB1 += 32;
    __syncthreads();
    bf16x8 av[4], bv[4];
#pragma unroll
    for (int i = 0; i < 4; i++)
      av[i] = *(const bf16x8*)(sA + (mw + 16 * i + row16) * 32 + k8);
#pragma unroll
    for (int j = 0; j < 4; j++)
      bv[j] = *(const bf16x8*)(sB + (nw + 16 * j + row16) * 32 + k8);
#pragma unroll
    for (int i = 0; i < 4; i++)
#pragma unroll
      for (int j = 0; j < 4; j++)
        acc[i][j] = __builtin_amdgcn_mfma_f32_16x16x32_bf16(av[i], bv[j], acc[i][j], 0, 0, 0);
    __syncthreads();
  }
  const int qr = (lane >> 4) * 4, cn = lane & 15;
#pragma unroll
  for (int i = 0; i < 4; i++) {
    const int m = m0 + mw + 16 * i + qr;
    const int b = m >> 11;
#pragma unroll
    for (int j = 0; j < 4; j++) {
      const int n = n0 + nw + 16 * j + cn;
      f32x4 v = acc[i][j];
      if constexpr (EPI == 0) {
        // in-proj: natural [m][d] stores; split xm / z
#pragma unroll
        for (int r = 0; r < 4; r++) {
          unsigned short* dst = (n < DI)
              ? g.h0 + (size_t)(m + r) * DI + n
              : g.h1 + (size_t)(m + r) * DI + (n - DI);
          *dst = f2bf(v[r]);
        }
      } else if constexpr (EPI == 1) {
        // x-proj split-K partial, transposed [z][n][m] fp32
        *(f32x4*)(g.f0 + ((size_t)(blockIdx.z * 128 + n)) * 8192 + m) = v;
      } else if constexpr (EPI == 2) {
        // dt-proj: +b_dt, softplus, bf16 [m][d]
        const float bn = g.c0[n];
#pragma unroll
        for (int r = 0; r < 4; r++) {
          float xx = v[r] + bn;
          g.h0[(size_t)(m + r) * DI + n] = f2bf((xx > 15.f) ? xx : __logf(1.f + __expf(xx)));
        }
      } else {
        // out-proj: out = x + gate * acc
        const float gate = g.c1[b * 3072 + 2048 + n];
#pragma unroll
        for (int r = 0; r < 4; r++) {
          size_t idx = (size_t)(m + r) * DM + n;
          g.f0[idx] = g.c0[idx] + gate * v[r];
        }
      }
    }
  }
}

// =================== causal depthwise conv (k=4) + silu, [m][d] -> [m][d] ===================
__global__ __launch_bounds__(256) void k_conv(const unsigned short* __restrict__ xm,
                                              const float* __restrict__ conv_w,
                                              const float* __restrict__ conv_b,
                                              unsigned short* __restrict__ u) {
  const int b = blockIdx.z;
  const int t = blockIdx.x * 32 + (threadIdx.x >> 3);
  const int d = blockIdx.y * 64 + (threadIdx.x & 7) * 8;
  const size_t rowbase = ((size_t)(b * L_ + t)) * DI + d;
  uint4 r3 = *(const uint4*)(xm + rowbase);
  uint4 r0 = make_uint4(0, 0, 0, 0), r1 = r0, r2 = r0;
  if (t >= 3) r0 = *(const uint4*)(xm + rowbase - 3 * DI);
  if (t >= 2) r1 = *(const uint4*)(xm + rowbase - 2 * DI);
  if (t >= 1) r2 = *(const uint4*)(xm + rowbase - 1 * DI);
  float x0[8], x1[8], x2[8], x3[8];
  const unsigned* p0 = (const unsigned*)&r0;
  const unsigned* p1 = (const unsigned*)&r1;
  const unsigned* p2 = (const unsigned*)&r2;
  const unsigned* p3 = (const unsigned*)&r3;
#pragma unroll
  for (int q = 0; q < 4; q++) {
    x0[2 * q] = bf2f(p0[q]); x0[2 * q + 1] = bf2f(p0[q] >> 16);
    x1[2 * q] = bf2f(p1[q]); x1[2 * q + 1] = bf2f(p1[q] >> 16);
    x2[2 * q] = bf2f(p2[q]); x2[2 * q + 1] = bf2f(p2[q] >> 16);
    x3[2 * q] = bf2f(p3[q]); x3[2 * q + 1] = bf2f(p3[q] >> 16);
  }
  const f32x4 cb0 = *(const f32x4*)(conv_b + d);
  const f32x4 cb1 = *(const f32x4*)(conv_b + d + 4);
  unsigned out[4];
#pragma unroll
  for (int j = 0; j < 8; j++) {
    const f32x4 wj = *(const f32x4*)(conv_w + (size_t)(d + j) * 4);
    const float cb = (j < 4) ? cb0[j] : cb1[j - 4];
    float a = cb + wj[0] * x0[j] + wj[1] * x1[j] + wj[2] * x2[j] + wj[3] * x3[j];
    unsigned short us = f2bf(silu_f(a));
    if (j & 1) out[j >> 1] |= ((unsigned)us << 16);
    else out[j >> 1] = us;
  }
  *(uint4*)(u + rowbase) = make_uint4(out[0], out[1], out[2], out[3]);
}

// =================== reduce split-K partials, split dt / pack BC[m][32] ===================
__global__ __launch_bounds__(256) void k_xsplit(const float* __restrict__ pt,
                                                unsigned short* __restrict__ dtb,
                                                float* __restrict__ BC) {
  const int bx = blockIdx.x;
  const int n = bx >> 5;
  const int m = ((bx & 31) << 8) + threadIdx.x;
  float v = pt[(size_t)n * 8192 + m] + pt[(size_t)(128 + n) * 8192 + m] +
            pt[(size_t)(256 + n) * 8192 + m] + pt[(size_t)(384 + n) * 8192 + m];
  if (n < 64) dtb[(size_t)m * 64 + n] = f2bf(v);
  else if (n < 80) BC[(size_t)m * 32 + (n - 64)] = v;
  else BC[(size_t)m * 32 + 16 + (n - 80)] = v;
}

// =================== scan phase A: local chunk scan, emit h_loc[16] + sum(delta) ===================
__global__ __launch_bounds__(256, 4) void k_scanA(const unsigned short* __restrict__ delta,
                                                  const unsigned short* __restrict__ u,
                                                  const float* __restrict__ BC,
                                                  const float* __restrict__ A_log,
                                                  float* __restrict__ hloc,
                                                  float* __restrict__ dsum) {
  const int b = blockIdx.y, c = blockIdx.z;
  const int d = blockIdx.x * 256 + threadIdx.x;
  const size_t mbase = (size_t)(b * L_ + c * TC);
  const unsigned short* dp = delta + mbase * DI + d;
  const unsigned short* up = u + mbase * DI + d;
  const float* bc = BC + mbase * 32;
  float As[16];
#pragma unroll
  for (int q = 0; q < 4; q++) {
    const f32x4 av = *(const f32x4*)(A_log + (size_t)d * 16 + q * 4);
#pragma unroll
    for (int j = 0; j < 4; j++) As[q * 4 + j] = -__expf(av[j]);
  }
  float h[16];
#pragma unroll
  for (int s = 0; s < 16; s++) h[s] = 0.f;
  float sd = 0.f;
  for (int t8 = 0; t8 < TC; t8 += 8) {
    float dv[8], uvf[8];
#pragma unroll
    for (int i = 0; i < 8; i++) dv[i] = bf2f(dp[(size_t)(t8 + i) * DI]);
#pragma unroll
    for (int i = 0; i < 8; i++) uvf[i] = bf2f(up[(size_t)(t8 + i) * DI]);
#pragma unroll
    for (int i = 0; i < 8; i++) {
      const float dvi = dv[i];
      const float w = dvi * uvf[i];
      sd += dvi;
      const float* bct = bc + (size_t)(t8 + i) * 32;
#pragma unroll
      for (int q = 0; q < 4; q++) {
        const f32x4 bq = *(const f32x4*)(bct + q * 4);
#pragma unroll
        for (int j = 0; j < 4; j++) {
          const int s = q * 4 + j;
          const float a = __expf(dvi * As[s]);
          h[s] = a * h[s] + w * bq[j];
        }
      }
    }
  }
  float* hl = hloc + (((size_t)(b * NC + c)) * DI + d) * 16;
#pragma unroll
  for (int q = 0; q < 4; q++) {
    f32x4 v = {h[q * 4], h[q * 4 + 1], h[q * 4 + 2], h[q * 4 + 3]};
    *(f32x4*)(hl + q * 4) = v;
  }
  dsum[((size_t)(b * NC + c)) * DI + d] = sd;
}

// =================== scan phase B: chunk prefix per (b,d) ===================
__global__ __launch_bounds__(256) void k_scanB(const float* __restrict__ hloc,
                                               const float* __restrict__ dsum,
                                               const float* __restrict__ A_log,
                                               float* __restrict__ hin) {
  const int i = blockIdx.x * 256 + threadIdx.x;   // 8192 = B*DI
  const int b = i >> 11, d = i & 2047;
  float As[16];
#pragma unroll
  for (int q = 0; q < 4; q++) {
    const f32x4 av = *(const f32x4*)(A_log + (size_t)d * 16 + q * 4);
#pragma unroll
    for (int j = 0; j < 4; j++) As[q * 4 + j] = -__expf(av[j]);
  }
  float H[16];
#pragma unroll
  for (int s = 0; s < 16; s++) H[s] = 0.f;
  for (int c = 0; c < NC; c++) {
    float* hp = hin + (((size_t)(b * NC + c)) * DI + d) * 16;
#pragma unroll
    for (int q = 0; q < 4; q++) {
      f32x4 v = {H[q * 4], H[q * 4 + 1], H[q * 4 + 2], H[q * 4 + 3]};
      *(f32x4*)(hp + q * 4) = v;
    }
    if (c < NC - 1) {
      const float sd = dsum[((size_t)(b * NC + c)) * DI + d];
      const float* hl = hloc + (((size_t)(b * NC + c)) * DI + d) * 16;
#pragma unroll
      for (int s = 0; s < 16; s++)
        H[s] = __expf(sd * As[s]) * H[s] + hl[s];
    }
  }
}

// =================== scan phase C: apply carry, y = C.h, fused skip + silu(z) gate ===================
__global__ __launch_bounds__(256, 4) void k_scanC(const unsigned short* __restrict__ delta,
                                                  const unsigned short* __restrict__ u,
                                                  const unsigned short* __restrict__ z,
                                                  const float* __restrict__ BC,
                                                  const float* __restrict__ A_log,
                                                  const float* __restrict__ Dsk,
                                                  const float* __restrict__ hin,
                                                  unsigned short* __restrict__ y) {
  const int b = blockIdx.y, c = blockIdx.z;
  const int d = blockIdx.x * 256 + threadIdx.x;
  const size_t mbase = (size_t)(b * L_ + c * TC);
  const unsigned short* dp = delta + mbase * DI + d;
  const unsigned short* up = u + mbase * DI + d;
  const unsigned short* zp = z + mbase * DI + d;
  const float* bc = BC + mbase * 32;
  float As[16];
#pragma unroll
  for (int q = 0; q < 4; q++) {
    const f32x4 av = *(const f32x4*)(A_log + (size_t)d * 16 + q * 4);
#pragma unroll
    for (int j = 0; j < 4; j++) As[q * 4 + j] = -__expf(av[j]);
  }
  const float dsk = Dsk[d];
  float h[16];
  const float* hp = hin + (((size_t)(b * NC + c)) * DI + d) * 16;
#pragma unroll
  for (int q = 0; q < 4; q++) {
    const f32x4 v = *(const f32x4*)(hp + q * 4);
#pragma unroll
    for (int j = 0; j < 4; j++) h[q * 4 + j] = v[j];
  }
  unsigned short* yp = y + mbase * DI + d;
  for (int t8 = 0; t8 < TC; t8 += 8) {
    float dv[8], uvf[8], zvf[8];
#pragma unroll
    for (int i = 0; i < 8; i++) dv[i] = bf2f(dp[(size_t)(t8 + i) * DI]);
#pragma unroll
    for (int i = 0; i < 8; i++) uvf[i] = bf2f(up[(size_t)(t8 + i) * DI]);
#pragma unroll
    for (int i = 0; i < 8; i++) zvf[i] = bf2f(zp[(size_t)(t8 + i) * DI]);
#pragma unroll
    for (int i = 0; i < 8; i++) {
      const float dvi = dv[i];
      const float w = dvi * uvf[i];
      const float* bct = bc + (size_t)(t8 + i) * 32;
      float y0 = 0.f, y1 = 0.f;
#pragma unroll
      for (int q = 0; q < 4; q++) {
        const f32x4 bq = *(const f32x4*)(bct + q * 4);
        const f32x4 cq = *(const f32x4*)(bct + 16 + q * 4);
#pragma unroll
        for (int j = 0; j < 4; j++) {
          const int s = q * 4 + j;
          const float a = __expf(dvi * As[s]);
          h[s] = a * h[s] + w * bq[j];
          if (j & 1) y1 += h[s] * cq[j]; else y0 += h[s] * cq[j];
        }
      }
      const float yt = (y0 + y1 + uvf[i] * dsk) * silu_f(zvf[i]);
      yp[(size_t)(t8 + i) * DI] = f2bf(yt);
    }
  }
}

// =================== launch ===================
extern "C" void kernel_launch(void* const* d_in, const int* in_sizes, int n_in,
                              void* d_out, int out_size, void* d_ws, size_t ws_size,
                              hipStream_t stream) {
  const float* x      = (const float*)d_in[0];
  const float* c      = (const float*)d_in[1];
  const float* W_in   = (const float*)d_in[2];
  const float* conv_w = (const float*)d_in[3];
  const float* conv_b = (const float*)d_in[4];
  const float* W_xp   = (const float*)d_in[5];
  const float* W_dt   = (const float*)d_in[6];
  const float* b_dt   = (const float*)d_in[7];
  const float* A_log  = (const float*)d_in[8];
  const float* D_skip = (const float*)d_in[9];
  const float* W_out  = (const float*)d_in[10];
  const float* W_ada  = (const float*)d_in[11];
  const float* b_ada  = (const float*)d_in[12];
  float* out = (float*)d_out;

  char* ws = (char*)d_ws;
  size_t off = 0;
  auto take = [&](size_t bytes) {
    char* p = ws + off;
    off += (bytes + 255) & ~(size_t)255;
    return p;
  };
  // Footprint <= R5 (known to fit). Aliases noted per-slot.
  float* mod             = (float*)take((size_t)4 * 3072 * 4);
  unsigned short* Wt_in  = (unsigned short*)take((size_t)4096 * 1024 * 2);
  unsigned short* Wt_out = (unsigned short*)take((size_t)1024 * 2048 * 2);
  unsigned short* Wt_xp  = (unsigned short*)take((size_t)128 * 2048 * 2);
  unsigned short* Wt_dt  = (unsigned short*)take((size_t)2048 * 64 * 2);
  unsigned short* h_bf   = (unsigned short*)take((size_t)8192 * 1024 * 2);      // 16MB; then part_T, then hin
  unsigned short* xm     = (unsigned short*)take((size_t)4 * 2048 * 2048 * 2);  // 32MB [m][d]; then y_bf
  unsigned short* z_bf   = (unsigned short*)take((size_t)4 * 2048 * 2048 * 2);  // 32MB [m][d]
  unsigned short* scanws = (unsigned short*)take((size_t)4 * 2048 * 2048 * 2);  // 32MB; hloc(16MB)+dsum(1MB)
  unsigned short* u_bf   = (unsigned short*)take((size_t)8192 * 2048 * 2);      // 32MB [m][d]; u==xc
  unsigned short* delta  = (unsigned short*)take((size_t)8192 * 2048 * 2);      // 32MB [m][d] bf16
  unsigned short* dt_bf  = (unsigned short*)take((size_t)8192 * 64 * 2);
  float* BC              = (float*)take((size_t)4 * 2048 * 32 * 4);             // [m][32]: B|C packed
  float* part_T = (float*)h_bf;                                   // dead after k_xsplit
  float* hin    = (float*)h_bf;                                   // 16MB exact; written by scanB
  float* hloc   = (float*)scanws;                                 // 16MB
  float* dsum   = (float*)(scanws + (size_t)8 * 1024 * 1024);     // +16MB, 1MB
  unsigned short* y_bf = xm;                                      // xm dead after conv

  // 1. weight convert+transpose (fused 4 jobs: 4096+2048+256+128 = 6528 blocks)
  k_wt4<<<6528, 256, 0, stream>>>(W_in, Wt_in, W_out, Wt_out, W_xp, Wt_xp, W_dt, Wt_dt);
  // 2. conditioning
  k_ada<<<dim3(12, 4), 256, 0, stream>>>(c, W_ada, b_ada, mod);
  // 3. LN + modulation
  k_ln<<<8192, 256, 0, stream>>>(x, mod, h_bf);
  // 4. in-proj -> xm[m][d], z[m][d]
  GArgs a1{h_bf, Wt_in, 1024, 1024, 1024, nullptr, xm, z_bf, nullptr, nullptr};
  k_gemm<0><<<dim3(64, 32), 256, 0, stream>>>(a1);
  // 5. conv + silu -> u[m][d]
  k_conv<<<dim3(64, 32, 4), 256, 0, stream>>>(xm, conv_w, conv_b, u_bf);
  // 6. x-proj (split-K)
  GArgs a2{u_bf, Wt_xp, 2048, 2048, 512, part_T, nullptr, nullptr, nullptr, nullptr};
  k_gemm<1><<<dim3(64, 1, 4), 256, 0, stream>>>(a2);
  // 7. reduce + split (dt rows; BC[m][32])
  k_xsplit<<<3072, 256, 0, stream>>>(part_T, dt_bf, BC);
  // 8. dt-proj + softplus -> delta[m][d] bf16
  GArgs a3{dt_bf, Wt_dt, 64, 64, 64, nullptr, delta, nullptr, b_dt, nullptr};
  k_gemm<2><<<dim3(64, 16), 256, 0, stream>>>(a3);
  // 9. chunked selective scan, [m][d] coalesced
  k_scanA<<<dim3(8, 4, NC - 1), 256, 0, stream>>>(delta, u_bf, BC, A_log, hloc, dsum);
  k_scanB<<<32, 256, 0, stream>>>(hloc, dsum, A_log, hin);
  k_scanC<<<dim3(8, 4, NC), 256, 0, stream>>>(delta, u_bf, z_bf, BC, A_log, D_skip, hin, y_bf);
  // 10. out-proj + residual + gate
  GArgs a4{y_bf, Wt_out, 2048, 2048, 2048, out, nullptr, nullptr, x, mod};
  k_gemm<3><<<dim3(64, 8), 256, 0, stream>>>(a4);
}